// Round 8
// baseline (505.906 us; speedup 1.0000x reference)
//
#include <hip/hip_runtime.h>
#include <hip/hip_bf16.h>
#include <math.h>

// Problem constants
constexpr int B_   = 2048;
constexpr int L_   = 64;
constexpr int V_   = 50000;
constexpr int IN_  = 300;
constexpr int M_   = 150;
constexpr int HID_ = 50;
constexpr int NC_  = 5;

// Padded dims — 608-wide gate-interleave (LeafE table layout)
constexpr int KP_  = 160;            // state row stride (bf16)
constexpr int GN_  = 608;            // gate-interleaved N: col = 4m+g, m<152
constexpr int GKC_ = 5;              // K chunks of 32 (150 -> 160)
// 640-wide gate-interleave (16-wave GEMM kernels)
constexpr int GN2_  = 640;           // col = 4m+g, m<160
constexpr int GNT2_ = 10;            // N-tiles per wave (16 waves: 4 mt x 4 nq)
constexpr int GCH2_ = GN2_ * 32;     // 20480 shorts per B chunk
constexpr int GQS2_ = GN2_ * 8;      // 5120 shorts per quad segment
// leaf GEMM
constexpr int LEAF_N  = 480;
constexpr int LEAF_NT = 15;
constexpr int LEAF_KC = 10;          // 300 -> 320
constexpr int LEAF_CH = LEAF_N * 32; // 15360
constexpr int LEAF_QS = LEAF_N * 8;  // 3840

typedef float f32x4  __attribute__((ext_vector_type(4)));
typedef short bf16x8 __attribute__((ext_vector_type(8)));
typedef short short4v __attribute__((ext_vector_type(4)));

__device__ __forceinline__ float rcp_f(float x) { return __builtin_amdgcn_rcpf(x); }
__device__ __forceinline__ float sgm(float x)   { return rcp_f(1.0f + __expf(-x)); }
__device__ __forceinline__ float tanh_f(float x){ return 1.0f - 2.0f * rcp_f(1.0f + __expf(2.0f * x)); }

__device__ __forceinline__ short f2bs(float f) {
    union { __hip_bfloat16 h; short s; } u; u.h = __float2bfloat16(f); return u.s;
}
__device__ __forceinline__ float bs2f(short s) {
    union { short s; __hip_bfloat16 h; } u; u.s = s; return __bfloat162float(u.h);
}

__device__ __forceinline__ void gl_lds16(const short* g, short* l) {
    __builtin_amdgcn_global_load_lds(
        (const __attribute__((address_space(1))) unsigned int*)g,
        (__attribute__((address_space(3))) unsigned int*)l, 16, 0, 0);
}

// ---------------------------------------------------------------------------
// K0: weight packing. Bg2 (640-wide gate-interleave), Bx (leaf).
// ---------------------------------------------------------------------------
__global__ __launch_bounds__(256) void prep_kernel(
    const float* __restrict__ Wioux, const float* __restrict__ Wiouh,
    const float* __restrict__ Wfh, short* __restrict__ Bg2, short* __restrict__ Bx)
{
    const int tid = blockIdx.x * blockDim.x + threadIdx.x;
    const int nthr = gridDim.x * blockDim.x;
    const int tot2 = GKC_ * GCH2_;
    for (int idx = tid; idx < tot2; idx += nthr) {
        const int kc = idx / GCH2_;
        int rem = idx % GCH2_;
        const int q = rem / GQS2_; rem %= GQS2_;
        const int n = rem / 8, j = rem % 8;
        const int k = kc * 32 + q * 8 + j;
        const int m = n >> 2, g = n & 3;
        float v = 0.0f;
        if (k < M_ && m < M_)
            v = (g < 3) ? Wiouh[k * 450 + g * 150 + m] : Wfh[k * M_ + m];
        Bg2[idx] = f2bs(v);
    }
    const int tot3 = LEAF_KC * LEAF_CH;
    for (int idx = tid; idx < tot3; idx += nthr) {
        const int kc = idx / LEAF_CH;
        int rem = idx % LEAF_CH;
        const int q = rem / LEAF_QS; rem %= LEAF_QS;
        const int n = rem / 8, j = rem % 8;
        const int k = kc * 32 + q * 8 + j;
        float v = (k < IN_ && n < 450) ? Wioux[k * 450 + n] : 0.0f;
        Bx[idx] = f2bs(v);
    }
}

// ---------------------------------------------------------------------------
// K1: leaf tables: emb @ Wioux -> LeafH/LeafC [V][160]  (unchanged, r5)
// ---------------------------------------------------------------------------
__global__ __launch_bounds__(512) void leaf_gemm(
    const float* __restrict__ emb, const short* __restrict__ Bx,
    const float* __restrict__ bioux, const float* __restrict__ biouh,
    short* __restrict__ LeafH, short* __restrict__ LeafC)
{
    __shared__ __align__(16) char smem[LEAF_CH * 2 + 64 * 64];
    short* Bs = (short*)smem;
    short* As = (short*)(smem + LEAF_CH * 2);
    float* Es = (float*)smem;

    const int t = threadIdx.x;
    const int row0 = blockIdx.x * 64;
    const int w = t >> 6, lane = t & 63;
    const int mt = w & 3, nt0 = (w >> 2) * LEAF_NT;
    const int lr = lane & 15, quad = lane >> 4;

    f32x4 acc[LEAF_NT];
    #pragma unroll
    for (int i = 0; i < LEAF_NT; i++) { acc[i][0] = 0; acc[i][1] = 0; acc[i][2] = 0; acc[i][3] = 0; }

    const int arow = t >> 3, apart = t & 7;
    const int av = row0 + arow;
    const int aq = apart >> 1, aj = (apart & 1) * 4;

    for (int kc = 0; kc < LEAF_KC; kc++) {
        const short* bsrc = Bx + (size_t)kc * LEAF_CH;
        #pragma unroll
        for (int i = 0; i < 3; i++)
            gl_lds16(bsrc + (i * 512 + t) * 8, Bs + (i * 512 + (t & ~63)) * 8);
        if (t < 384)
            gl_lds16(bsrc + (1536 + t) * 8, Bs + (1536 + (t & ~63)) * 8);
        {
            const int k0 = kc * 32 + apart * 4;
            float4 x = make_float4(0.f, 0.f, 0.f, 0.f);
            if (av < V_ && k0 < IN_) x = *(const float4*)&emb[(size_t)av * IN_ + k0];
            short4v s;
            s[0] = f2bs(x.x); s[1] = f2bs(x.y); s[2] = f2bs(x.z); s[3] = f2bs(x.w);
            *(short4v*)&As[aq * 512 + arow * 8 + aj] = s;
        }
        __syncthreads();
        bf16x8 a = *(const bf16x8*)&As[quad * 512 + (mt * 16 + lr) * 8];
        #pragma unroll
        for (int i = 0; i < LEAF_NT; i++) {
            bf16x8 b = *(const bf16x8*)&Bs[quad * LEAF_QS + ((nt0 + i) * 16 + lr) * 8];
            acc[i] = __builtin_amdgcn_mfma_f32_16x16x32_bf16(a, b, acc[i], 0, 0, 0);
        }
        __syncthreads();
    }

    for (int mc = 0; mc < 4; mc++) {
        if (mt == mc) {
            #pragma unroll
            for (int i = 0; i < LEAF_NT; i++) {
                const int col = (nt0 + i) * 16 + lr;
                #pragma unroll
                for (int r = 0; r < 4; r++) Es[(quad * 4 + r) * LEAF_N + col] = acc[i][r];
            }
        }
        __syncthreads();
        for (int p = t; p < 16 * KP_; p += 512) {
            const int rl = p / KP_, n = p % KP_;
            const int v = row0 + mc * 16 + rl;
            if (v < V_) {
                if (n < M_) {
                    const float i_ = Es[rl * LEAF_N + n]       + bioux[n]       + biouh[n];
                    const float o_ = Es[rl * LEAF_N + n + 150] + bioux[n + 150] + biouh[n + 150];
                    const float u_ = Es[rl * LEAF_N + n + 300] + bioux[n + 300] + biouh[n + 300];
                    const float c = sgm(i_) * tanh_f(u_);
                    const float h = sgm(o_) * tanh_f(c);
                    LeafH[(size_t)v * KP_ + n] = f2bs(h);
                    LeafC[(size_t)v * KP_ + n] = f2bs(c);
                } else {
                    LeafH[(size_t)v * KP_ + n] = 0;
                    LeafC[(size_t)v * KP_ + n] = 0;
                }
            }
        }
        __syncthreads();
    }
}

// ---------------------------------------------------------------------------
// K2: per-vocab level-0 tables — 1024 threads, 16 waves, Bg2 (r7, proven).
// LeafE output stays 608-wide.
// ---------------------------------------------------------------------------
__global__ __launch_bounds__(1024) void leafGF_gemm(
    const short* __restrict__ LeafH, const short* __restrict__ LeafC,
    const short* __restrict__ Bg2, const float* __restrict__ bfh,
    short* __restrict__ LeafE)
{
    __shared__ __align__(16) char smem[GCH2_ * 2 + 4096 + KP_ * 64 * 2 + 600];
    short* Bs   = (short*)smem;                        // 40960 B
    short* As   = (short*)(smem + GCH2_ * 2);          // 4096 B
    short* CinS = (short*)(smem + GCH2_ * 2 + 4096);   // 20480 B
    float* bfs  = (float*)(smem + GCH2_ * 2 + 4096 + KP_ * 64 * 2);
    short* Os = (short*)smem;                          // 32*608*2 = 38912 B

    const int t = threadIdx.x;
    const int v0 = blockIdx.x * 64;
    const int w = t >> 6, lane = t & 63;
    const int mt = w & 3, nt0 = (w >> 2) * GNT2_;
    const int lr = lane & 15, quad = lane >> 4;
    const int c = lane & 15;

    if (t < 150) bfs[t] = bfh[t];
    const short* csrc = LeafC + (size_t)v0 * KP_;
    gl_lds16(csrc + t * 8, CinS + (t & ~63) * 8);
    if (t < 256)
        gl_lds16(csrc + (1024 + t) * 8, CinS + (1024 + (t & ~63)) * 8);

    f32x4 acc[GNT2_];
    #pragma unroll
    for (int i = 0; i < GNT2_; i++) { acc[i][0] = 0; acc[i][1] = 0; acc[i][2] = 0; acc[i][3] = 0; }

    const int arow = t & 63, apart = t >> 6;   // apart 0..3 for t<256
    const size_t srow = (size_t)((v0 + arow < V_) ? (v0 + arow) : 0);
    const short* asrc = LeafH + srow * KP_ + apart * 8;

    for (int kc = 0; kc < GKC_; kc++) {
        const short* bsrc = Bg2 + (size_t)kc * GCH2_;
        #pragma unroll
        for (int i = 0; i < 2; i++)
            gl_lds16(bsrc + (i * 1024 + t) * 8, Bs + (i * 1024 + (t & ~63)) * 8);
        if (t < 512)
            gl_lds16(bsrc + (2048 + t) * 8, Bs + (2048 + (t & ~63)) * 8);
        if (t < 256)
            gl_lds16(asrc + kc * 32, As + (t & ~63) * 8);
        __syncthreads();
        bf16x8 a = *(const bf16x8*)&As[quad * 512 + (mt * 16 + lr) * 8];
        #pragma unroll
        for (int i = 0; i < GNT2_; i++) {
            bf16x8 b = *(const bf16x8*)&Bs[quad * GQS2_ + ((nt0 + i) * 16 + lr) * 8];
            acc[i] = __builtin_amdgcn_mfma_f32_16x16x32_bf16(a, b, acc[i], 0, 0, 0);
        }
        __syncthreads();
    }

    for (int ph = 0; ph < 2; ph++) {
        if ((mt >> 1) == ph) {
            const int rbase = 16 * (mt & 1) + 4 * quad;
            #pragma unroll
            for (int i = 0; i < GNT2_; i++) {
                const int col = (nt0 + i) * 16 + c;
                if (col < GN_) {
                    const int m = col >> 2, g = col & 3;
                    #pragma unroll
                    for (int r = 0; r < 4; r++) {
                        short ov;
                        if (g == 3) {
                            if (m < M_) {
                                const float cc = bs2f(CinS[(32 * ph + rbase + r) * KP_ + m]);
                                ov = f2bs(sgm(acc[i][r] + bfs[m]) * cc);
                            } else ov = 0;
                        } else ov = f2bs(acc[i][r]);
                        Os[(rbase + r) * GN_ + col] = ov;
                    }
                }
            }
        }
        __syncthreads();
        const int vb = v0 + 32 * ph;
        const int4* os4 = (const int4*)Os;
        for (int u = t; u < 2432; u += 1024) {
            const int row = u / 76;
            if (vb + row < V_)
                ((int4*)(LeafE + (size_t)(vb + row) * GN_))[u - row * 76] = os4[u];
        }
        __syncthreads();
    }
}

// ---------------------------------------------------------------------------
// Shared in-register LSTM epilogue (gate-interleaved C).
// CS = CinS row stride; TNT = N-tiles per wave.
// ---------------------------------------------------------------------------
template<int CS, int TNT>
__device__ __forceinline__ void level_epilogue(
    const f32x4* acc, int mt, int nt0, int lane,
    const short* CinS, const float* bias_s, short* Hs, short* Cs)
{
    const int q = lane >> 4, c = lane & 15, g = c & 3, lb = lane & ~3;
    #pragma unroll
    for (int i = 0; i < TNT; i++) {
        const int col = (nt0 + i) * 16 + c;
        const int m = col >> 2;
        const float vA = acc[i][0] + acc[i][1];
        const float vB = acc[i][2] + acc[i][3];
        const float iA = __shfl(vA, lb), oA = __shfl(vA, lb + 1), uA = __shfl(vA, lb + 2);
        const float iB = __shfl(vB, lb), oB = __shfl(vB, lb + 1), uB = __shfl(vB, lb + 2);
        const float fA0 = __shfl(acc[i][0], lb + 3), fA1 = __shfl(acc[i][1], lb + 3);
        const float fB0 = __shfl(acc[i][2], lb + 3), fB1 = __shfl(acc[i][3], lb + 3);
        if (g < 2 && m < M_) {
            const float iv = g ? iB : iA, ov = g ? oB : oA, uv = g ? uB : uA;
            const float fl = g ? fB0 : fA0, fr = g ? fB1 : fA1;
            const int node = 8 * mt + 2 * q + g;
            const int ch = 16 * mt + 4 * q + 2 * g;
            const float cl = bs2f(CinS[ch * CS + m]);
            const float cr = bs2f(CinS[(ch + 1) * CS + m]);
            const float bf = bias_s[450 + m];
            const float cv = sgm(iv + bias_s[m]) * tanh_f(uv + bias_s[m + 300])
                           + sgm(fl + bf) * cl + sgm(fr + bf) * cr;
            const float hv = sgm(ov + bias_s[m + 150]) * tanh_f(cv);
            Hs[node * KP_ + m] = f2bs(hv);
            Cs[node * KP_ + m] = f2bs(cv);
        }
    }
}

// ---------------------------------------------------------------------------
// K3: level 1 with fused level-0 gather — RESTRUCTURED to 16 waves:
// 1024 threads, Bg2 640-wide, acc = 10 tiles (40 VGPR). One block/CU gives
// the same 16 waves/CU as the old (512,4) 2-block config but WITHOUT the
// forced-cap spill (~95 MB/dispatch scratch traffic in r4-r7).
// Gather: 64 rows x 16 slots x 3 quads (16 waves issue the LeafE reads).
// ---------------------------------------------------------------------------
__global__ __launch_bounds__(1024, 4) void level1_fused(
    const int* __restrict__ ltok, const int* __restrict__ rtok,
    const short* __restrict__ LeafE, const short* __restrict__ Bg2,
    const float* __restrict__ biouh, const float* __restrict__ bfh,
    short* __restrict__ Hout, short* __restrict__ Cout)
{
    constexpr int CS1 = 152;                                   // CinS row stride
    __shared__ __align__(16) char smem[GCH2_ * 2 + 20480 + 64 * CS1 * 2 + 2400]; // 83296 B
    short* Bs     = (short*)smem;                              // 40960 B
    short* AsF    = (short*)(smem + GCH2_ * 2);                // 20480 B persistent A
    short* CinS   = (short*)(smem + GCH2_ * 2 + 20480);        // 19456 B
    float* bias_s = (float*)(smem + GCH2_ * 2 + 20480 + 64 * CS1 * 2); // 2400 B
    short* Hs = Bs;
    short* Cs = Bs + 32 * KP_;

    const int t = threadIdx.x;
    const int out0 = blockIdx.x * 32;
    const int w = t >> 6, lane = t & 63;
    const int mt = w & 3, nt0 = (w >> 2) * GNT2_;
    const int lr = lane & 15, quad = lane >> 4;

    if (t < 600) bias_s[t] = (t < 450) ? biouh[t] : bfh[t - 450];
    __syncthreads();

    // ---- fused level-0: compute 64 node h/c rows into AsF / CinS ----
    {
        const int row = t >> 4, slot = t & 15;
        const int gidx = blockIdx.x * 128 + 2 * row;
        const int* tsrc = (gidx < B_ * L_) ? (ltok + gidx) : (rtok + gidx - B_ * L_);
        const short* el = LeafE + (size_t)tsrc[0] * GN_;
        const short* er = LeafE + (size_t)tsrc[1] * GN_;
        #pragma unroll
        for (int s = 0; s < 3; s++) {
            const int Q = slot + 16 * s;                   // m-quad 0..47
            if (Q < 40) {
                short4v hq = {0, 0, 0, 0}, cq = {0, 0, 0, 0};
                if (Q < 38) {
                    union { int4 v[2]; short s16[16]; } ue, ur;
                    ue.v[0] = *(const int4*)(el + Q * 16);
                    ue.v[1] = *(const int4*)(el + Q * 16 + 8);
                    ur.v[0] = *(const int4*)(er + Q * 16);
                    ur.v[1] = *(const int4*)(er + Q * 16 + 8);
                    #pragma unroll
                    for (int jj = 0; jj < 4; jj++) {
                        const int m = 4 * Q + jj;
                        if (m < M_) {
                            const float i_ = bs2f(ue.s16[4 * jj])     + bs2f(ur.s16[4 * jj])     + bias_s[m];
                            const float o_ = bs2f(ue.s16[4 * jj + 1]) + bs2f(ur.s16[4 * jj + 1]) + bias_s[m + 150];
                            const float u_ = bs2f(ue.s16[4 * jj + 2]) + bs2f(ur.s16[4 * jj + 2]) + bias_s[m + 300];
                            const float fc = bs2f(ue.s16[4 * jj + 3]) + bs2f(ur.s16[4 * jj + 3]);
                            const float cv = sgm(i_) * tanh_f(u_) + fc;
                            const float hv = sgm(o_) * tanh_f(cv);
                            hq[jj] = f2bs(hv); cq[jj] = f2bs(cv);
                        }
                    }
                }
                const int m0 = 4 * Q;
                const int kc = m0 >> 5, q = (m0 >> 3) & 3, j0 = m0 & 7;
                *(short4v*)&AsF[(kc * 4 + q) * 512 + row * 8 + j0] = hq;  // zeros pad A
                if (Q < 38)
                    *(short4v*)&CinS[row * CS1 + m0] = cq;
            }
        }
    }

    f32x4 acc[GNT2_];
    #pragma unroll
    for (int i = 0; i < GNT2_; i++) { acc[i][0] = 0; acc[i][1] = 0; acc[i][2] = 0; acc[i][3] = 0; }

    for (int kc = 0; kc < GKC_; kc++) {
        const short* bsrc = Bg2 + (size_t)kc * GCH2_;
        #pragma unroll
        for (int i = 0; i < 2; i++)
            gl_lds16(bsrc + (i * 1024 + t) * 8, Bs + (i * 1024 + (t & ~63)) * 8);
        if (t < 512)
            gl_lds16(bsrc + (2048 + t) * 8, Bs + (2048 + (t & ~63)) * 8);
        __syncthreads();
        bf16x8 a = *(const bf16x8*)&AsF[kc * 2048 + quad * 512 + (mt * 16 + lr) * 8];
        #pragma unroll
        for (int i = 0; i < GNT2_; i++) {
            bf16x8 b = *(const bf16x8*)&Bs[quad * GQS2_ + ((nt0 + i) * 16 + lr) * 8];
            acc[i] = __builtin_amdgcn_mfma_f32_16x16x32_bf16(a, b, acc[i], 0, 0, 0);
        }
        __syncthreads();
    }

    if (t < 320) { const int node = t / 10, mm = 150 + t % 10;
                   Hs[node * KP_ + mm] = 0; Cs[node * KP_ + mm] = 0; }
    level_epilogue<CS1, GNT2_>(acc, mt, nt0, lane, CinS, bias_s, Hs, Cs);
    __syncthreads();
    int4* Hg = (int4*)(Hout + (size_t)out0 * KP_);
    int4* Cg = (int4*)(Cout + (size_t)out0 * KP_);
    const int4* hs4 = (const int4*)Hs;
    const int4* cs4 = (const int4*)Cs;
    for (int u = t; u < 1280; u += 1024) {
        if (u < 640) Hg[u] = hs4[u]; else Cg[u - 640] = cs4[u - 640];
    }
}

// ---------------------------------------------------------------------------
// K4: internal levels 2..5 — 1024 threads, 16 waves, Bg2 (r7, proven).
// ---------------------------------------------------------------------------
__global__ __launch_bounds__(1024) void level_gemm(
    const short* __restrict__ Hin, const short* __restrict__ Cin,
    const short* __restrict__ Bg2,
    const float* __restrict__ biouh, const float* __restrict__ bfh,
    short* __restrict__ Hout, short* __restrict__ Cout)
{
    __shared__ __align__(16) char smem[GCH2_ * 2 + 4096 + 20480 + 2400];
    short* Bs     = (short*)smem;                        // 40960 B
    short* As     = (short*)(smem + GCH2_ * 2);
    short* CinS   = (short*)(smem + GCH2_ * 2 + 4096);
    float* bias_s = (float*)(smem + GCH2_ * 2 + 4096 + 20480);
    short* Hs = Bs;
    short* Cs = Bs + 32 * KP_;

    const int t = threadIdx.x;
    const int row0 = blockIdx.x * 64, out0 = blockIdx.x * 32;
    const int w = t >> 6, lane = t & 63;
    const int mt = w & 3, nt0 = (w >> 2) * GNT2_;
    const int lr = lane & 15, quad = lane >> 4;

    if (t < 600) bias_s[t] = (t < 450) ? biouh[t] : bfh[t - 450];
    const short* csrc = Cin + (size_t)row0 * KP_;
    gl_lds16(csrc + t * 8, CinS + (t & ~63) * 8);
    if (t < 256)
        gl_lds16(csrc + (1024 + t) * 8, CinS + (1024 + (t & ~63)) * 8);

    f32x4 acc[GNT2_];
    #pragma unroll
    for (int i = 0; i < GNT2_; i++) { acc[i][0] = 0; acc[i][1] = 0; acc[i][2] = 0; acc[i][3] = 0; }

    const short* asrc = Hin + (size_t)(row0 + (t & 63)) * KP_ + (t >> 6) * 8;

    for (int kc = 0; kc < GKC_; kc++) {
        const short* bsrc = Bg2 + (size_t)kc * GCH2_;
        #pragma unroll
        for (int i = 0; i < 2; i++)
            gl_lds16(bsrc + (i * 1024 + t) * 8, Bs + (i * 1024 + (t & ~63)) * 8);
        if (t < 512)
            gl_lds16(bsrc + (2048 + t) * 8, Bs + (2048 + (t & ~63)) * 8);
        if (t < 256)
            gl_lds16(asrc + kc * 32, As + (t & ~63) * 8);
        __syncthreads();
        bf16x8 a = *(const bf16x8*)&As[quad * 512 + (mt * 16 + lr) * 8];
        #pragma unroll
        for (int i = 0; i < GNT2_; i++) {
            bf16x8 b = *(const bf16x8*)&Bs[quad * GQS2_ + ((nt0 + i) * 16 + lr) * 8];
            acc[i] = __builtin_amdgcn_mfma_f32_16x16x32_bf16(a, b, acc[i], 0, 0, 0);
        }
        __syncthreads();
    }

    if (t < 320) { const int node = t / 10, mm = 150 + t % 10;
                   Hs[node * KP_ + mm] = 0; Cs[node * KP_ + mm] = 0; }
    level_epilogue<KP_, GNT2_>(acc, mt, nt0, lane, CinS, bias_s, Hs, Cs);
    __syncthreads();
    int4* Hg = (int4*)(Hout + (size_t)out0 * KP_);
    int4* Cg = (int4*)(Cout + (size_t)out0 * KP_);
    const int4* hs4 = (const int4*)Hs;
    const int4* cs4 = (const int4*)Cs;
    for (int u = t; u < 1280; u += 1024) {
        if (u < 640) Hg[u] = hs4[u]; else Cg[u - 640] = cs4[u - 640];
    }
}

// ---------------------------------------------------------------------------
// K5: similarity head (one wave per pair).
// ---------------------------------------------------------------------------
__global__ __launch_bounds__(64) void head_kernel(
    const short* __restrict__ RootH,
    const float* __restrict__ Wh, const float* __restrict__ bh,
    const float* __restrict__ Wp, const float* __restrict__ bp,
    float* __restrict__ out)
{
    __shared__ float vec[2 * M_];
    __shared__ float mid[HID_];
    __shared__ float lg[NC_];
    __shared__ float lse;

    const int b = blockIdx.x;
    const int t = threadIdx.x;
    const short* lh = RootH + (size_t)b * KP_;
    const short* rh = RootH + (size_t)(B_ + b) * KP_;

    for (int i = t; i < M_; i += 64) {
        const float a = bs2f(lh[i]), c = bs2f(rh[i]);
        vec[i]      = a * c;
        vec[M_ + i] = fabsf(a - c);
    }
    __syncthreads();

    for (int j = t; j < HID_; j += 64) {
        float acc = bh[j];
        for (int k = 0; k < 2 * M_; k++) acc += vec[k] * Wh[k * HID_ + j];
        mid[j] = sgm(acc);
    }
    __syncthreads();

    if (t < NC_) {
        float acc = bp[t];
        for (int k = 0; k < HID_; k++) acc += mid[k] * Wp[k * NC_ + t];
        lg[t] = acc;
    }
    __syncthreads();

    if (t == 0) {
        float mx = lg[0];
        for (int i = 1; i < NC_; i++) mx = fmaxf(mx, lg[i]);
        float s = 0.0f;
        for (int i = 0; i < NC_; i++) s += expf(lg[i] - mx);
        lse = mx + logf(s);
    }
    __syncthreads();

    if (t < NC_) out[b * NC_ + t] = lg[t] - lse;
}

// ---------------------------------------------------------------------------
extern "C" void kernel_launch(void* const* d_in, const int* in_sizes, int n_in,
                              void* d_out, int out_size, void* d_ws, size_t ws_size,
                              hipStream_t stream)
{
    const int*   ltok  = (const int*)d_in[0];
    const int*   rtok  = (const int*)d_in[1];
    const float* emb   = (const float*)d_in[2];
    const float* Wioux = (const float*)d_in[3];
    const float* bioux = (const float*)d_in[4];
    const float* Wiouh = (const float*)d_in[5];
    const float* biouh = (const float*)d_in[6];
    const float* Wfh   = (const float*)d_in[9];
    const float* bfh   = (const float*)d_in[10];
    const float* Wh    = (const float*)d_in[11];
    const float* bh    = (const float*)d_in[12];
    const float* Wp    = (const float*)d_in[13];
    const float* bp    = (const float*)d_in[14];
    float* out = (float*)d_out;

    char* ws = (char*)d_ws;
    size_t off = 0;
    auto carve = [&](size_t bytes) { char* p = ws + off; off += (bytes + 255) & ~(size_t)255; return p; };
    short* Bg2   = (short*)carve((size_t)GKC_ * GCH2_ * 2);
    short* Bx    = (short*)carve((size_t)LEAF_KC * LEAF_CH * 2);
    short* LeafH = (short*)carve((size_t)V_ * KP_ * 2);      // 16 MB
    short* LeafC = (short*)carve((size_t)V_ * KP_ * 2);      // 16 MB
    short* LeafE = (short*)carve((size_t)V_ * GN_ * 2);      // 60.8 MB
    short* HA    = (short*)carve((size_t)65536 * KP_ * 2);   // 21 MB
    short* CA    = (short*)carve((size_t)65536 * KP_ * 2);   // 21 MB
    short* HB    = (short*)carve((size_t)32768 * KP_ * 2);   // 10.5 MB
    short* CB    = (short*)carve((size_t)32768 * KP_ * 2);   // 10.5 MB

    hipLaunchKernelGGL(prep_kernel, dim3(128), dim3(256), 0, stream, Wioux, Wiouh, Wfh, Bg2, Bx);
    hipLaunchKernelGGL(leaf_gemm, dim3((V_ + 63) / 64), dim3(512), 0, stream,
                       emb, Bx, bioux, biouh, LeafH, LeafC);
    hipLaunchKernelGGL(leafGF_gemm, dim3((V_ + 63) / 64), dim3(1024), 0, stream,
                       LeafH, LeafC, Bg2, bfh, LeafE);
    // level 1 (fused level-0 gather): 131072 nodes -> 65536 rows
    hipLaunchKernelGGL(level1_fused, dim3(2048), dim3(1024), 0, stream,
                       ltok, rtok, LeafE, Bg2, biouh, bfh, HA, CA);
    // levels 2..5
    hipLaunchKernelGGL(level_gemm, dim3(1024), dim3(1024), 0, stream,
                       HA, CA, Bg2, biouh, bfh, HB, CB);
    hipLaunchKernelGGL(level_gemm, dim3(512), dim3(1024), 0, stream,
                       HB, CB, Bg2, biouh, bfh, HA, CA);
    hipLaunchKernelGGL(level_gemm, dim3(256), dim3(1024), 0, stream,
                       HA, CA, Bg2, biouh, bfh, HB, CB);
    hipLaunchKernelGGL(level_gemm, dim3(128), dim3(1024), 0, stream,
                       HB, CB, Bg2, biouh, bfh, HA, CA);
    hipLaunchKernelGGL(head_kernel, dim3(B_), dim3(64), 0, stream, HA, Wh, bh, Wp, bp, out);
}

// Round 9
// 491.963 us; speedup vs baseline: 1.0283x; 1.0283x over previous
//
#include <hip/hip_runtime.h>
#include <hip/hip_bf16.h>
#include <math.h>

// Problem constants
constexpr int B_   = 2048;
constexpr int L_   = 64;
constexpr int V_   = 50000;
constexpr int IN_  = 300;
constexpr int M_   = 150;
constexpr int HID_ = 50;
constexpr int NC_  = 5;

// Padded dims — 608-wide gate-interleave (LeafE table / level1 path)
constexpr int KP_  = 160;            // state row stride (bf16)
constexpr int GN_  = 608;            // gate-interleaved N: col = 4m+g, m<152
constexpr int GNT_ = 19;             // N-tiles per wave (8-wave level1)
constexpr int GKC_ = 5;              // K chunks of 32 (150 -> 160)
constexpr int GCH_ = GN_ * 32;       // shorts per B chunk (19456)
constexpr int GQS_ = GN_ * 8;        // shorts per quad segment (4864)
// 640-wide gate-interleave (16-wave GEMM kernels)
constexpr int GN2_  = 640;           // col = 4m+g, m<160
constexpr int GNT2_ = 10;            // N-tiles per wave (16 waves: 4 mt x 4 nq)
constexpr int GCH2_ = GN2_ * 32;     // 20480 shorts per B chunk
constexpr int GQS2_ = GN2_ * 8;      // 5120 shorts per quad segment
// leaf GEMM
constexpr int LEAF_N  = 480;
constexpr int LEAF_NT = 15;
constexpr int LEAF_KC = 10;          // 300 -> 320
constexpr int LEAF_CH = LEAF_N * 32; // 15360
constexpr int LEAF_QS = LEAF_N * 8;  // 3840

typedef float f32x4  __attribute__((ext_vector_type(4)));
typedef short bf16x8 __attribute__((ext_vector_type(8)));
typedef short short4v __attribute__((ext_vector_type(4)));

__device__ __forceinline__ float rcp_f(float x) { return __builtin_amdgcn_rcpf(x); }
__device__ __forceinline__ float sgm(float x)   { return rcp_f(1.0f + __expf(-x)); }
__device__ __forceinline__ float tanh_f(float x){ return 1.0f - 2.0f * rcp_f(1.0f + __expf(2.0f * x)); }

__device__ __forceinline__ short f2bs(float f) {
    union { __hip_bfloat16 h; short s; } u; u.h = __float2bfloat16(f); return u.s;
}
__device__ __forceinline__ float bs2f(short s) {
    union { short s; __hip_bfloat16 h; } u; u.s = s; return __bfloat162float(u.h);
}

__device__ __forceinline__ void gl_lds16(const short* g, short* l) {
    __builtin_amdgcn_global_load_lds(
        (const __attribute__((address_space(1))) unsigned int*)g,
        (__attribute__((address_space(3))) unsigned int*)l, 16, 0, 0);
}

// ---------------------------------------------------------------------------
// K0: weight packing. Bg (608-wide, level1), Bg2 (640-wide), Bx (leaf).
// ---------------------------------------------------------------------------
__global__ __launch_bounds__(256) void prep_kernel(
    const float* __restrict__ Wioux, const float* __restrict__ Wiouh,
    const float* __restrict__ Wfh, short* __restrict__ Bg,
    short* __restrict__ Bg2, short* __restrict__ Bx)
{
    const int tid = blockIdx.x * blockDim.x + threadIdx.x;
    const int nthr = gridDim.x * blockDim.x;
    const int tot1 = GKC_ * GCH_;
    for (int idx = tid; idx < tot1; idx += nthr) {
        const int kc = idx / GCH_;
        int rem = idx % GCH_;
        const int q = rem / GQS_; rem %= GQS_;
        const int n = rem / 8, j = rem % 8;
        const int k = kc * 32 + q * 8 + j;
        const int m = n >> 2, g = n & 3;
        float v = 0.0f;
        if (k < M_ && m < M_)
            v = (g < 3) ? Wiouh[k * 450 + g * 150 + m] : Wfh[k * M_ + m];
        Bg[idx] = f2bs(v);
    }
    const int tot2 = GKC_ * GCH2_;
    for (int idx = tid; idx < tot2; idx += nthr) {
        const int kc = idx / GCH2_;
        int rem = idx % GCH2_;
        const int q = rem / GQS2_; rem %= GQS2_;
        const int n = rem / 8, j = rem % 8;
        const int k = kc * 32 + q * 8 + j;
        const int m = n >> 2, g = n & 3;
        float v = 0.0f;
        if (k < M_ && m < M_)
            v = (g < 3) ? Wiouh[k * 450 + g * 150 + m] : Wfh[k * M_ + m];
        Bg2[idx] = f2bs(v);
    }
    const int tot3 = LEAF_KC * LEAF_CH;
    for (int idx = tid; idx < tot3; idx += nthr) {
        const int kc = idx / LEAF_CH;
        int rem = idx % LEAF_CH;
        const int q = rem / LEAF_QS; rem %= LEAF_QS;
        const int n = rem / 8, j = rem % 8;
        const int k = kc * 32 + q * 8 + j;
        float v = (k < IN_ && n < 450) ? Wioux[k * 450 + n] : 0.0f;
        Bx[idx] = f2bs(v);
    }
}

// ---------------------------------------------------------------------------
// K1: leaf tables: emb @ Wioux -> LeafH/LeafC [V][160]  (unchanged)
// ---------------------------------------------------------------------------
__global__ __launch_bounds__(512) void leaf_gemm(
    const float* __restrict__ emb, const short* __restrict__ Bx,
    const float* __restrict__ bioux, const float* __restrict__ biouh,
    short* __restrict__ LeafH, short* __restrict__ LeafC)
{
    __shared__ __align__(16) char smem[LEAF_CH * 2 + 64 * 64];
    short* Bs = (short*)smem;
    short* As = (short*)(smem + LEAF_CH * 2);
    float* Es = (float*)smem;

    const int t = threadIdx.x;
    const int row0 = blockIdx.x * 64;
    const int w = t >> 6, lane = t & 63;
    const int mt = w & 3, nt0 = (w >> 2) * LEAF_NT;
    const int lr = lane & 15, quad = lane >> 4;

    f32x4 acc[LEAF_NT];
    #pragma unroll
    for (int i = 0; i < LEAF_NT; i++) { acc[i][0] = 0; acc[i][1] = 0; acc[i][2] = 0; acc[i][3] = 0; }

    const int arow = t >> 3, apart = t & 7;
    const int av = row0 + arow;
    const int aq = apart >> 1, aj = (apart & 1) * 4;

    for (int kc = 0; kc < LEAF_KC; kc++) {
        const short* bsrc = Bx + (size_t)kc * LEAF_CH;
        #pragma unroll
        for (int i = 0; i < 3; i++)
            gl_lds16(bsrc + (i * 512 + t) * 8, Bs + (i * 512 + (t & ~63)) * 8);
        if (t < 384)
            gl_lds16(bsrc + (1536 + t) * 8, Bs + (1536 + (t & ~63)) * 8);
        {
            const int k0 = kc * 32 + apart * 4;
            float4 x = make_float4(0.f, 0.f, 0.f, 0.f);
            if (av < V_ && k0 < IN_) x = *(const float4*)&emb[(size_t)av * IN_ + k0];
            short4v s;
            s[0] = f2bs(x.x); s[1] = f2bs(x.y); s[2] = f2bs(x.z); s[3] = f2bs(x.w);
            *(short4v*)&As[aq * 512 + arow * 8 + aj] = s;
        }
        __syncthreads();
        bf16x8 a = *(const bf16x8*)&As[quad * 512 + (mt * 16 + lr) * 8];
        #pragma unroll
        for (int i = 0; i < LEAF_NT; i++) {
            bf16x8 b = *(const bf16x8*)&Bs[quad * LEAF_QS + ((nt0 + i) * 16 + lr) * 8];
            acc[i] = __builtin_amdgcn_mfma_f32_16x16x32_bf16(a, b, acc[i], 0, 0, 0);
        }
        __syncthreads();
    }

    for (int mc = 0; mc < 4; mc++) {
        if (mt == mc) {
            #pragma unroll
            for (int i = 0; i < LEAF_NT; i++) {
                const int col = (nt0 + i) * 16 + lr;
                #pragma unroll
                for (int r = 0; r < 4; r++) Es[(quad * 4 + r) * LEAF_N + col] = acc[i][r];
            }
        }
        __syncthreads();
        for (int p = t; p < 16 * KP_; p += 512) {
            const int rl = p / KP_, n = p % KP_;
            const int v = row0 + mc * 16 + rl;
            if (v < V_) {
                if (n < M_) {
                    const float i_ = Es[rl * LEAF_N + n]       + bioux[n]       + biouh[n];
                    const float o_ = Es[rl * LEAF_N + n + 150] + bioux[n + 150] + biouh[n + 150];
                    const float u_ = Es[rl * LEAF_N + n + 300] + bioux[n + 300] + biouh[n + 300];
                    const float c = sgm(i_) * tanh_f(u_);
                    const float h = sgm(o_) * tanh_f(c);
                    LeafH[(size_t)v * KP_ + n] = f2bs(h);
                    LeafC[(size_t)v * KP_ + n] = f2bs(c);
                } else {
                    LeafH[(size_t)v * KP_ + n] = 0;
                    LeafC[(size_t)v * KP_ + n] = 0;
                }
            }
        }
        __syncthreads();
    }
}

// ---------------------------------------------------------------------------
// K2: per-vocab level-0 tables — 1024 threads, 16 waves (r7, proven).
// NEW: folds 0.5*biouh into the G slots (g<3), so level1's gather needs no
// bias at all (G_l + G_r reconstructs biouh exactly).
// ---------------------------------------------------------------------------
__global__ __launch_bounds__(1024) void leafGF_gemm(
    const short* __restrict__ LeafH, const short* __restrict__ LeafC,
    const short* __restrict__ Bg2, const float* __restrict__ biouh,
    const float* __restrict__ bfh, short* __restrict__ LeafE)
{
    __shared__ __align__(16) char smem[GCH2_ * 2 + 4096 + KP_ * 64 * 2 + 2400];
    short* Bs     = (short*)smem;                        // 40960 B
    short* As     = (short*)(smem + GCH2_ * 2);          // 4096 B
    short* CinS   = (short*)(smem + GCH2_ * 2 + 4096);   // 20480 B
    float* bias_s = (float*)(smem + GCH2_ * 2 + 4096 + KP_ * 64 * 2); // 2400 B
    short* Os = (short*)smem;                            // 32*608*2 = 38912 B

    const int t = threadIdx.x;
    const int v0 = blockIdx.x * 64;
    const int w = t >> 6, lane = t & 63;
    const int mt = w & 3, nt0 = (w >> 2) * GNT2_;
    const int lr = lane & 15, quad = lane >> 4;
    const int c = lane & 15;

    if (t < 600) bias_s[t] = (t < 450) ? biouh[t] : bfh[t - 450];
    const short* csrc = LeafC + (size_t)v0 * KP_;
    gl_lds16(csrc + t * 8, CinS + (t & ~63) * 8);
    if (t < 256)
        gl_lds16(csrc + (1024 + t) * 8, CinS + (1024 + (t & ~63)) * 8);

    f32x4 acc[GNT2_];
    #pragma unroll
    for (int i = 0; i < GNT2_; i++) { acc[i][0] = 0; acc[i][1] = 0; acc[i][2] = 0; acc[i][3] = 0; }

    const int arow = t & 63, apart = t >> 6;   // apart 0..3 for t<256
    const size_t srow = (size_t)((v0 + arow < V_) ? (v0 + arow) : 0);
    const short* asrc = LeafH + srow * KP_ + apart * 8;

    for (int kc = 0; kc < GKC_; kc++) {
        const short* bsrc = Bg2 + (size_t)kc * GCH2_;
        #pragma unroll
        for (int i = 0; i < 2; i++)
            gl_lds16(bsrc + (i * 1024 + t) * 8, Bs + (i * 1024 + (t & ~63)) * 8);
        if (t < 512)
            gl_lds16(bsrc + (2048 + t) * 8, Bs + (2048 + (t & ~63)) * 8);
        if (t < 256)
            gl_lds16(asrc + kc * 32, As + (t & ~63) * 8);
        __syncthreads();
        bf16x8 a = *(const bf16x8*)&As[quad * 512 + (mt * 16 + lr) * 8];
        #pragma unroll
        for (int i = 0; i < GNT2_; i++) {
            bf16x8 b = *(const bf16x8*)&Bs[quad * GQS2_ + ((nt0 + i) * 16 + lr) * 8];
            acc[i] = __builtin_amdgcn_mfma_f32_16x16x32_bf16(a, b, acc[i], 0, 0, 0);
        }
        __syncthreads();
    }

    for (int ph = 0; ph < 2; ph++) {
        if ((mt >> 1) == ph) {
            const int rbase = 16 * (mt & 1) + 4 * quad;
            #pragma unroll
            for (int i = 0; i < GNT2_; i++) {
                const int col = (nt0 + i) * 16 + c;
                if (col < GN_) {
                    const int m = col >> 2, g = col & 3;
                    #pragma unroll
                    for (int r = 0; r < 4; r++) {
                        short ov;
                        if (g == 3) {
                            if (m < M_) {
                                const float cc = bs2f(CinS[(32 * ph + rbase + r) * KP_ + m]);
                                ov = f2bs(sgm(acc[i][r] + bias_s[450 + m]) * cc);
                            } else ov = 0;
                        } else {
                            float gv = acc[i][r];
                            if (m < M_) gv += 0.5f * bias_s[g * 150 + m];  // fold bias
                            ov = f2bs(gv);
                        }
                        Os[(rbase + r) * GN_ + col] = ov;
                    }
                }
            }
        }
        __syncthreads();
        const int vb = v0 + 32 * ph;
        const int4* os4 = (const int4*)Os;
        for (int u = t; u < 2432; u += 1024) {
            const int row = u / 76;
            if (vb + row < V_)
                ((int4*)(LeafE + (size_t)(vb + row) * GN_))[u - row * 76] = os4[u];
        }
        __syncthreads();
    }
}

// ---------------------------------------------------------------------------
// Shared in-register LSTM epilogue (gate-interleaved C) for level_gemm.
// ---------------------------------------------------------------------------
template<int CS, int TNT>
__device__ __forceinline__ void level_epilogue(
    const f32x4* acc, int mt, int nt0, int lane,
    const short* CinS, const float* bias_s, short* Hs, short* Cs)
{
    const int q = lane >> 4, c = lane & 15, g = c & 3, lb = lane & ~3;
    #pragma unroll
    for (int i = 0; i < TNT; i++) {
        const int col = (nt0 + i) * 16 + c;
        const int m = col >> 2;
        const float vA = acc[i][0] + acc[i][1];
        const float vB = acc[i][2] + acc[i][3];
        const float iA = __shfl(vA, lb), oA = __shfl(vA, lb + 1), uA = __shfl(vA, lb + 2);
        const float iB = __shfl(vB, lb), oB = __shfl(vB, lb + 1), uB = __shfl(vB, lb + 2);
        const float fA0 = __shfl(acc[i][0], lb + 3), fA1 = __shfl(acc[i][1], lb + 3);
        const float fB0 = __shfl(acc[i][2], lb + 3), fB1 = __shfl(acc[i][3], lb + 3);
        if (g < 2 && m < M_) {
            const float iv = g ? iB : iA, ov = g ? oB : oA, uv = g ? uB : uA;
            const float fl = g ? fB0 : fA0, fr = g ? fB1 : fA1;
            const int node = 8 * mt + 2 * q + g;
            const int ch = 16 * mt + 4 * q + 2 * g;
            const float cl = bs2f(CinS[ch * CS + m]);
            const float cr = bs2f(CinS[(ch + 1) * CS + m]);
            const float bf = bias_s[450 + m];
            const float cv = sgm(iv + bias_s[m]) * tanh_f(uv + bias_s[m + 300])
                           + sgm(fl + bf) * cl + sgm(fr + bf) * cr;
            const float hv = sgm(ov + bias_s[m + 150]) * tanh_f(cv);
            Hs[node * KP_ + m] = f2bs(hv);
            Cs[node * KP_ + m] = f2bs(cv);
        }
    }
}

// ---------------------------------------------------------------------------
// level1 helpers: per-half epilogue to PACKED REGISTERS (Hs/Cs alias Bs,
// which half 1 still needs), bias via L2-broadcast global loads.
// ---------------------------------------------------------------------------
template<int T0, int TN>
__device__ __forceinline__ void epi_half_pack(
    const f32x4* acc, int mt, int nt0, int lane, const short* CinS,
    const float* __restrict__ biouh, const float* __restrict__ bfh,
    unsigned int* pack)
{
    const int q = lane >> 4, c = lane & 15, g = c & 3, lb = lane & ~3;
    #pragma unroll
    for (int i = 0; i < TN; i++) {
        const int col = (nt0 + T0 + i) * 16 + c;
        const int m = col >> 2;
        const float vA = acc[i][0] + acc[i][1];
        const float vB = acc[i][2] + acc[i][3];
        const float iA = __shfl(vA, lb), oA = __shfl(vA, lb + 1), uA = __shfl(vA, lb + 2);
        const float iB = __shfl(vB, lb), oB = __shfl(vB, lb + 1), uB = __shfl(vB, lb + 2);
        const float fA0 = __shfl(acc[i][0], lb + 3), fA1 = __shfl(acc[i][1], lb + 3);
        const float fB0 = __shfl(acc[i][2], lb + 3), fB1 = __shfl(acc[i][3], lb + 3);
        unsigned int pk = 0;
        if (g < 2 && m < M_) {
            const float iv = g ? iB : iA, ov = g ? oB : oA, uv = g ? uB : uA;
            const float fl = g ? fB0 : fA0, fr = g ? fB1 : fA1;
            const int ch = 16 * mt + 4 * q + 2 * g;
            const float cl = bs2f(CinS[ch * 152 + m]);
            const float cr = bs2f(CinS[(ch + 1) * 152 + m]);
            const float bf = bfh[m];
            const float cv = sgm(iv + biouh[m]) * tanh_f(uv + biouh[m + 300])
                           + sgm(fl + bf) * cl + sgm(fr + bf) * cr;
            const float hv = sgm(ov + biouh[m + 150]) * tanh_f(cv);
            pk = ((unsigned int)(unsigned short)f2bs(hv) << 16)
               |  (unsigned int)(unsigned short)f2bs(cv);
        }
        pack[i] = pk;
    }
}

template<int T0, int TN>
__device__ __forceinline__ void unpack_half(
    const unsigned int* pack, int mt, int nt0, int lane, short* Hs, short* Cs)
{
    const int q = lane >> 4, c = lane & 15, g = c & 3;
    #pragma unroll
    for (int i = 0; i < TN; i++) {
        const int col = (nt0 + T0 + i) * 16 + c;
        const int m = col >> 2;
        if (g < 2 && m < M_) {
            const int node = 8 * mt + 2 * q + g;
            Hs[node * KP_ + m] = (short)(pack[i] >> 16);
            Cs[node * KP_ + m] = (short)(pack[i] & 0xffff);
        }
    }
}

// ---------------------------------------------------------------------------
// K3: level 1 with fused level-0 gather — 512 threads, (512,4), 2 blocks/CU
// (phase overlap, r7-proven), N-SPLIT K-loop: 19 tiles as 10+9 passes so
// acc peaks at 40 VGPR -> no spill under the 128 cap (r8 proved spill-free
// codegen; r7 proved 2-block overlap; this combines both).
// Gather needs no bias (folded into LeafE by leafGF); epilogue bias from
// global (L2-broadcast). LDS = 78848 B (proven 2-block geometry).
// ---------------------------------------------------------------------------
__global__ __launch_bounds__(512, 4) void level1_fused(
    const int* __restrict__ ltok, const int* __restrict__ rtok,
    const short* __restrict__ LeafE, const short* __restrict__ Bg,
    const float* __restrict__ biouh, const float* __restrict__ bfh,
    short* __restrict__ Hout, short* __restrict__ Cout)
{
    constexpr int CS1 = 152;                                   // CinS row stride
    __shared__ __align__(16) char smem[GCH_ * 2 + 20480 + 64 * CS1 * 2]; // 78848 B
    short* Bs     = (short*)smem;                              // 38912 B
    short* AsF    = (short*)(smem + GCH_ * 2);                 // 20480 B persistent A
    short* CinS   = (short*)(smem + GCH_ * 2 + 20480);         // 19456 B
    short* Hs = Bs;
    short* Cs = Bs + 32 * KP_;

    const int t = threadIdx.x;
    const int out0 = blockIdx.x * 32;
    const int w = t >> 6, lane = t & 63;
    const int mt = w & 3, nt0 = (w >> 2) * GNT_;
    const int lr = lane & 15, quad = lane >> 4;

    // ---- fused level-0 gather: 64 node h/c rows into AsF / CinS (no bias) --
    {
        const int row = t >> 3, qs = t & 7;
        const int gidx = blockIdx.x * 128 + 2 * row;
        const int* tsrc = (gidx < B_ * L_) ? (ltok + gidx) : (rtok + gidx - B_ * L_);
        const short* el = LeafE + (size_t)tsrc[0] * GN_;
        const short* er = LeafE + (size_t)tsrc[1] * GN_;

        union U { int4 v[2]; short s16[16]; };
        U ue, ur, uen, urn;
        ue.v[0] = *(const int4*)(el + qs * 16);
        ue.v[1] = *(const int4*)(el + qs * 16 + 8);
        ur.v[0] = *(const int4*)(er + qs * 16);
        ur.v[1] = *(const int4*)(er + qs * 16 + 8);

        #pragma unroll 1
        for (int s = 0; s < 5; s++) {
            const int Q  = qs + 8 * s;
            const int Qn = Q + 8;
            if (s < 4 && Qn < 38) {
                uen.v[0] = *(const int4*)(el + Qn * 16);
                uen.v[1] = *(const int4*)(el + Qn * 16 + 8);
                urn.v[0] = *(const int4*)(er + Qn * 16);
                urn.v[1] = *(const int4*)(er + Qn * 16 + 8);
            }
            short4v hq = {0, 0, 0, 0}, cq = {0, 0, 0, 0};
            if (Q < 38) {
                #pragma unroll
                for (int jj = 0; jj < 4; jj++) {
                    const int m = 4 * Q + jj;
                    if (m < M_) {
                        const float i_ = bs2f(ue.s16[4 * jj])     + bs2f(ur.s16[4 * jj]);
                        const float o_ = bs2f(ue.s16[4 * jj + 1]) + bs2f(ur.s16[4 * jj + 1]);
                        const float u_ = bs2f(ue.s16[4 * jj + 2]) + bs2f(ur.s16[4 * jj + 2]);
                        const float fc = bs2f(ue.s16[4 * jj + 3]) + bs2f(ur.s16[4 * jj + 3]);
                        const float cv = sgm(i_) * tanh_f(u_) + fc;
                        const float hv = sgm(o_) * tanh_f(cv);
                        hq[jj] = f2bs(hv); cq[jj] = f2bs(cv);
                    }
                }
            }
            const int m0 = 4 * Q;
            const int kc = m0 >> 5, q = (m0 >> 3) & 3, j0 = m0 & 7;
            *(short4v*)&AsF[(kc * 4 + q) * 512 + row * 8 + j0] = hq;   // zeros pad A
            if (Q < 38)
                *(short4v*)&CinS[row * CS1 + m0] = cq;
            ue = uen; ur = urn;
        }
    }

    unsigned int packA[10], packB[9];
    f32x4 acc[10];

    // -------- N-half 0: tiles nt0+0 .. nt0+9 --------
    #pragma unroll
    for (int i = 0; i < 10; i++) { acc[i][0] = 0; acc[i][1] = 0; acc[i][2] = 0; acc[i][3] = 0; }
    for (int kc = 0; kc < GKC_; kc++) {
        const short* bsrc = Bg + (size_t)kc * GCH_;
        #pragma unroll
        for (int i = 0; i < 4; i++)
            gl_lds16(bsrc + (i * 512 + t) * 8, Bs + (i * 512 + (t & ~63)) * 8);
        if (t < 384)
            gl_lds16(bsrc + (2048 + t) * 8, Bs + (2048 + (t & ~63)) * 8);
        __syncthreads();
        bf16x8 a = *(const bf16x8*)&AsF[kc * 2048 + quad * 512 + (mt * 16 + lr) * 8];
        #pragma unroll
        for (int i = 0; i < 10; i++) {
            bf16x8 b = *(const bf16x8*)&Bs[quad * GQS_ + ((nt0 + i) * 16 + lr) * 8];
            acc[i] = __builtin_amdgcn_mfma_f32_16x16x32_bf16(a, b, acc[i], 0, 0, 0);
        }
        __syncthreads();
    }
    epi_half_pack<0, 10>(acc, mt, nt0, lane, CinS, biouh, bfh, packA);

    // -------- N-half 1: tiles nt0+10 .. nt0+18 --------
    #pragma unroll
    for (int i = 0; i < 9; i++) { acc[i][0] = 0; acc[i][1] = 0; acc[i][2] = 0; acc[i][3] = 0; }
    for (int kc = 0; kc < GKC_; kc++) {
        const short* bsrc = Bg + (size_t)kc * GCH_;
        #pragma unroll
        for (int i = 0; i < 4; i++)
            gl_lds16(bsrc + (i * 512 + t) * 8, Bs + (i * 512 + (t & ~63)) * 8);
        if (t < 384)
            gl_lds16(bsrc + (2048 + t) * 8, Bs + (2048 + (t & ~63)) * 8);
        __syncthreads();
        bf16x8 a = *(const bf16x8*)&AsF[kc * 2048 + quad * 512 + (mt * 16 + lr) * 8];
        #pragma unroll
        for (int i = 0; i < 9; i++) {
            bf16x8 b = *(const bf16x8*)&Bs[quad * GQS_ + ((nt0 + 10 + i) * 16 + lr) * 8];
            acc[i] = __builtin_amdgcn_mfma_f32_16x16x32_bf16(a, b, acc[i], 0, 0, 0);
        }
        __syncthreads();
    }
    epi_half_pack<10, 9>(acc, mt, nt0, lane, CinS, biouh, bfh, packB);

    // -------- write phase: unpack into Hs/Cs (Bs now dead) --------
    if (t < 320) { const int node = t / 10, mm = 150 + t % 10;
                   Hs[node * KP_ + mm] = 0; Cs[node * KP_ + mm] = 0; }
    unpack_half<0, 10>(packA, mt, nt0, lane, Hs, Cs);
    unpack_half<10, 9>(packB, mt, nt0, lane, Hs, Cs);
    __syncthreads();
    int4* Hg = (int4*)(Hout + (size_t)out0 * KP_);
    int4* Cg = (int4*)(Cout + (size_t)out0 * KP_);
    const int4* hs4 = (const int4*)Hs;
    const int4* cs4 = (const int4*)Cs;
    for (int u = t; u < 1280; u += 512) {
        if (u < 640) Hg[u] = hs4[u]; else Cg[u - 640] = cs4[u - 640];
    }
}

// ---------------------------------------------------------------------------
// K4: internal levels 2..5 — 1024 threads, 16 waves, Bg2 (r7, proven).
// ---------------------------------------------------------------------------
__global__ __launch_bounds__(1024) void level_gemm(
    const short* __restrict__ Hin, const short* __restrict__ Cin,
    const short* __restrict__ Bg2,
    const float* __restrict__ biouh, const float* __restrict__ bfh,
    short* __restrict__ Hout, short* __restrict__ Cout)
{
    __shared__ __align__(16) char smem[GCH2_ * 2 + 4096 + 20480 + 2400];
    short* Bs     = (short*)smem;                        // 40960 B
    short* As     = (short*)(smem + GCH2_ * 2);
    short* CinS   = (short*)(smem + GCH2_ * 2 + 4096);
    float* bias_s = (float*)(smem + GCH2_ * 2 + 4096 + 20480);
    short* Hs = Bs;
    short* Cs = Bs + 32 * KP_;

    const int t = threadIdx.x;
    const int row0 = blockIdx.x * 64, out0 = blockIdx.x * 32;
    const int w = t >> 6, lane = t & 63;
    const int mt = w & 3, nt0 = (w >> 2) * GNT2_;
    const int lr = lane & 15, quad = lane >> 4;

    if (t < 600) bias_s[t] = (t < 450) ? biouh[t] : bfh[t - 450];
    const short* csrc = Cin + (size_t)row0 * KP_;
    gl_lds16(csrc + t * 8, CinS + (t & ~63) * 8);
    if (t < 256)
        gl_lds16(csrc + (1024 + t) * 8, CinS + (1024 + (t & ~63)) * 8);

    f32x4 acc[GNT2_];
    #pragma unroll
    for (int i = 0; i < GNT2_; i++) { acc[i][0] = 0; acc[i][1] = 0; acc[i][2] = 0; acc[i][3] = 0; }

    const short* asrc = Hin + (size_t)(row0 + (t & 63)) * KP_ + (t >> 6) * 8;

    for (int kc = 0; kc < GKC_; kc++) {
        const short* bsrc = Bg2 + (size_t)kc * GCH2_;
        #pragma unroll
        for (int i = 0; i < 2; i++)
            gl_lds16(bsrc + (i * 1024 + t) * 8, Bs + (i * 1024 + (t & ~63)) * 8);
        if (t < 512)
            gl_lds16(bsrc + (2048 + t) * 8, Bs + (2048 + (t & ~63)) * 8);
        if (t < 256)
            gl_lds16(asrc + kc * 32, As + (t & ~63) * 8);
        __syncthreads();
        bf16x8 a = *(const bf16x8*)&As[quad * 512 + (mt * 16 + lr) * 8];
        #pragma unroll
        for (int i = 0; i < GNT2_; i++) {
            bf16x8 b = *(const bf16x8*)&Bs[quad * GQS2_ + ((nt0 + i) * 16 + lr) * 8];
            acc[i] = __builtin_amdgcn_mfma_f32_16x16x32_bf16(a, b, acc[i], 0, 0, 0);
        }
        __syncthreads();
    }

    if (t < 320) { const int node = t / 10, mm = 150 + t % 10;
                   Hs[node * KP_ + mm] = 0; Cs[node * KP_ + mm] = 0; }
    level_epilogue<KP_, GNT2_>(acc, mt, nt0, lane, CinS, bias_s, Hs, Cs);
    __syncthreads();
    int4* Hg = (int4*)(Hout + (size_t)out0 * KP_);
    int4* Cg = (int4*)(Cout + (size_t)out0 * KP_);
    const int4* hs4 = (const int4*)Hs;
    const int4* cs4 = (const int4*)Cs;
    for (int u = t; u < 1280; u += 1024) {
        if (u < 640) Hg[u] = hs4[u]; else Cg[u - 640] = cs4[u - 640];
    }
}

// ---------------------------------------------------------------------------
// K5: similarity head (one wave per pair).
// ---------------------------------------------------------------------------
__global__ __launch_bounds__(64) void head_kernel(
    const short* __restrict__ RootH,
    const float* __restrict__ Wh, const float* __restrict__ bh,
    const float* __restrict__ Wp, const float* __restrict__ bp,
    float* __restrict__ out)
{
    __shared__ float vec[2 * M_];
    __shared__ float mid[HID_];
    __shared__ float lg[NC_];
    __shared__ float lse;

    const int b = blockIdx.x;
    const int t = threadIdx.x;
    const short* lh = RootH + (size_t)b * KP_;
    const short* rh = RootH + (size_t)(B_ + b) * KP_;

    for (int i = t; i < M_; i += 64) {
        const float a = bs2f(lh[i]), c = bs2f(rh[i]);
        vec[i]      = a * c;
        vec[M_ + i] = fabsf(a - c);
    }
    __syncthreads();

    for (int j = t; j < HID_; j += 64) {
        float acc = bh[j];
        for (int k = 0; k < 2 * M_; k++) acc += vec[k] * Wh[k * HID_ + j];
        mid[j] = sgm(acc);
    }
    __syncthreads();

    if (t < NC_) {
        float acc = bp[t];
        for (int k = 0; k < HID_; k++) acc += mid[k] * Wp[k * NC_ + t];
        lg[t] = acc;
    }
    __syncthreads();

    if (t == 0) {
        float mx = lg[0];
        for (int i = 1; i < NC_; i++) mx = fmaxf(mx, lg[i]);
        float s = 0.0f;
        for (int i = 0; i < NC_; i++) s += expf(lg[i] - mx);
        lse = mx + logf(s);
    }
    __syncthreads();

    if (t < NC_) out[b * NC_ + t] = lg[t] - lse;
}

// ---------------------------------------------------------------------------
extern "C" void kernel_launch(void* const* d_in, const int* in_sizes, int n_in,
                              void* d_out, int out_size, void* d_ws, size_t ws_size,
                              hipStream_t stream)
{
    const int*   ltok  = (const int*)d_in[0];
    const int*   rtok  = (const int*)d_in[1];
    const float* emb   = (const float*)d_in[2];
    const float* Wioux = (const float*)d_in[3];
    const float* bioux = (const float*)d_in[4];
    const float* Wiouh = (const float*)d_in[5];
    const float* biouh = (const float*)d_in[6];
    const float* Wfh   = (const float*)d_in[9];
    const float* bfh   = (const float*)d_in[10];
    const float* Wh    = (const float*)d_in[11];
    const float* bh    = (const float*)d_in[12];
    const float* Wp    = (const float*)d_in[13];
    const float* bp    = (const float*)d_in[14];
    float* out = (float*)d_out;

    char* ws = (char*)d_ws;
    size_t off = 0;
    auto carve = [&](size_t bytes) { char* p = ws + off; off += (bytes + 255) & ~(size_t)255; return p; };
    short* Bg    = (short*)carve((size_t)GKC_ * GCH_ * 2);
    short* Bg2   = (short*)carve((size_t)GKC_ * GCH2_ * 2);
    short* Bx    = (short*)carve((size_t)LEAF_KC * LEAF_CH * 2);
    short* LeafH = (short*)carve((size_t)V_ * KP_ * 2);      // 16 MB
    short* LeafC = (short*)carve((size_t)V_ * KP_ * 2);      // 16 MB
    short* LeafE = (short*)carve((size_t)V_ * GN_ * 2);      // 60.8 MB
    short* HA    = (short*)carve((size_t)65536 * KP_ * 2);   // 21 MB
    short* CA    = (short*)carve((size_t)65536 * KP_ * 2);   // 21 MB
    short* HB    = (short*)carve((size_t)32768 * KP_ * 2);   // 10.5 MB
    short* CB    = (short*)carve((size_t)32768 * KP_ * 2);   // 10.5 MB

    hipLaunchKernelGGL(prep_kernel, dim3(128), dim3(256), 0, stream, Wioux, Wiouh, Wfh, Bg, Bg2, Bx);
    hipLaunchKernelGGL(leaf_gemm, dim3((V_ + 63) / 64), dim3(512), 0, stream,
                       emb, Bx, bioux, biouh, LeafH, LeafC);
    hipLaunchKernelGGL(leafGF_gemm, dim3((V_ + 63) / 64), dim3(1024), 0, stream,
                       LeafH, LeafC, Bg2, biouh, bfh, LeafE);
    // level 1 (fused level-0 gather): 131072 nodes -> 65536 rows
    hipLaunchKernelGGL(level1_fused, dim3(2048), dim3(512), 0, stream,
                       ltok, rtok, LeafE, Bg, biouh, bfh, HA, CA);
    // levels 2..5
    hipLaunchKernelGGL(level_gemm, dim3(1024), dim3(1024), 0, stream,
                       HA, CA, Bg2, biouh, bfh, HB, CB);
    hipLaunchKernelGGL(level_gemm, dim3(512), dim3(1024), 0, stream,
                       HB, CB, Bg2, biouh, bfh, HA, CA);
    hipLaunchKernelGGL(level_gemm, dim3(256), dim3(1024), 0, stream,
                       HA, CA, Bg2, biouh, bfh, HB, CB);
    hipLaunchKernelGGL(level_gemm, dim3(128), dim3(1024), 0, stream,
                       HB, CB, Bg2, biouh, bfh, HA, CA);
    hipLaunchKernelGGL(head_kernel, dim3(B_), dim3(64), 0, stream, HA, Wh, bh, Wp, bp, out);
}

// Round 11
// 483.392 us; speedup vs baseline: 1.0466x; 1.0177x over previous
//
#include <hip/hip_runtime.h>
#include <hip/hip_bf16.h>
#include <math.h>

// Problem constants
constexpr int B_   = 2048;
constexpr int L_   = 64;
constexpr int V_   = 50000;
constexpr int IN_  = 300;
constexpr int M_   = 150;
constexpr int HID_ = 50;
constexpr int NC_  = 5;

// Padded dims — 608-wide gate-interleave (LeafE table / level1 path)
constexpr int KP_  = 160;            // state row stride (bf16)
constexpr int GN_  = 608;            // gate-interleaved N: col = 4m+g, m<152
constexpr int GNT_ = 19;             // N-tiles per wave (8-wave level1)
constexpr int GKC_ = 5;              // K chunks of 32 (150 -> 160)
// level1 split-packed Bg (BgS): section 0 = pass-0 tiles {0..9,19..28} (20
// slots, 320 cols); section 1 = pass-1 tiles {10..18,29..37} (18 slots).
constexpr int S0_CH  = 10240;        // shorts per kc chunk (sec 0)
constexpr int S0_QS  = 2560;         // shorts per quad segment (sec 0)
constexpr int S0_TOT = GKC_ * S0_CH; // 51200
constexpr int S1_CH  = 9216;
constexpr int S1_QS  = 2304;
constexpr int S1_TOT = GKC_ * S1_CH; // 46080
// 640-wide gate-interleave (16-wave GEMM kernels)
constexpr int GN2_  = 640;           // col = 4m+g, m<160
constexpr int GNT2_ = 10;            // N-tiles per wave (16 waves: 4 mt x 4 nq)
constexpr int GCH2_ = GN2_ * 32;     // 20480 shorts per B chunk
constexpr int GQS2_ = GN2_ * 8;      // 5120 shorts per quad segment
// leaf GEMM
constexpr int LEAF_N  = 480;
constexpr int LEAF_NT = 15;
constexpr int LEAF_KC = 10;          // 300 -> 320
constexpr int LEAF_CH = LEAF_N * 32; // 15360
constexpr int LEAF_QS = LEAF_N * 8;  // 3840

typedef float f32x4  __attribute__((ext_vector_type(4)));
typedef short bf16x8 __attribute__((ext_vector_type(8)));
typedef short short4v __attribute__((ext_vector_type(4)));

__device__ __forceinline__ float rcp_f(float x) { return __builtin_amdgcn_rcpf(x); }
__device__ __forceinline__ float sgm(float x)   { return rcp_f(1.0f + __expf(-x)); }
__device__ __forceinline__ float tanh_f(float x){ return 1.0f - 2.0f * rcp_f(1.0f + __expf(2.0f * x)); }

__device__ __forceinline__ short f2bs(float f) {
    union { __hip_bfloat16 h; short s; } u; u.h = __float2bfloat16(f); return u.s;
}
__device__ __forceinline__ float bs2f(short s) {
    union { short s; __hip_bfloat16 h; } u; u.s = s; return __bfloat162float(u.h);
}

__device__ __forceinline__ void gl_lds16(const short* g, short* l) {
    __builtin_amdgcn_global_load_lds(
        (const __attribute__((address_space(1))) unsigned int*)g,
        (__attribute__((address_space(3))) unsigned int*)l, 16, 0, 0);
}

// level1 pass-slot -> global tile id
__device__ __forceinline__ int s0_tile(int slot) { return slot < 10 ? slot : 19 + (slot - 10); }
__device__ __forceinline__ int s1_tile(int slot) { return slot < 9 ? 10 + slot : 29 + (slot - 9); }

// ---------------------------------------------------------------------------
// K0: weight packing. BgS (level1 split-pack), Bg2 (640-wide), Bx (leaf).
// ---------------------------------------------------------------------------
__global__ __launch_bounds__(256) void prep_kernel(
    const float* __restrict__ Wioux, const float* __restrict__ Wiouh,
    const float* __restrict__ Wfh, short* __restrict__ BgS,
    short* __restrict__ Bg2, short* __restrict__ Bx)
{
    const int tid = blockIdx.x * blockDim.x + threadIdx.x;
    const int nthr = gridDim.x * blockDim.x;
    const int tot1 = S0_TOT + S1_TOT;
    for (int idx = tid; idx < tot1; idx += nthr) {
        int n, k;
        if (idx < S0_TOT) {
            const int kc = idx / S0_CH;
            int rem = idx % S0_CH;
            const int q = rem / S0_QS; rem %= S0_QS;
            const int sc = rem / 8, j = rem % 8;
            n = s0_tile(sc >> 4) * 16 + (sc & 15);
            k = kc * 32 + q * 8 + j;
        } else {
            const int idx1 = idx - S0_TOT;
            const int kc = idx1 / S1_CH;
            int rem = idx1 % S1_CH;
            const int q = rem / S1_QS; rem %= S1_QS;
            const int sc = rem / 8, j = rem % 8;
            n = s1_tile(sc >> 4) * 16 + (sc & 15);
            k = kc * 32 + q * 8 + j;
        }
        const int m = n >> 2, g = n & 3;
        float v = 0.0f;
        if (k < M_ && m < M_)
            v = (g < 3) ? Wiouh[k * 450 + g * 150 + m] : Wfh[k * M_ + m];
        BgS[idx] = f2bs(v);
    }
    const int tot2 = GKC_ * GCH2_;
    for (int idx = tid; idx < tot2; idx += nthr) {
        const int kc = idx / GCH2_;
        int rem = idx % GCH2_;
        const int q = rem / GQS2_; rem %= GQS2_;
        const int n = rem / 8, j = rem % 8;
        const int k = kc * 32 + q * 8 + j;
        const int m = n >> 2, g = n & 3;
        float v = 0.0f;
        if (k < M_ && m < M_)
            v = (g < 3) ? Wiouh[k * 450 + g * 150 + m] : Wfh[k * M_ + m];
        Bg2[idx] = f2bs(v);
    }
    const int tot3 = LEAF_KC * LEAF_CH;
    for (int idx = tid; idx < tot3; idx += nthr) {
        const int kc = idx / LEAF_CH;
        int rem = idx % LEAF_CH;
        const int q = rem / LEAF_QS; rem %= LEAF_QS;
        const int n = rem / 8, j = rem % 8;
        const int k = kc * 32 + q * 8 + j;
        float v = (k < IN_ && n < 450) ? Wioux[k * 450 + n] : 0.0f;
        Bx[idx] = f2bs(v);
    }
}

// ---------------------------------------------------------------------------
// K1: leaf tables: emb @ Wioux -> LeafH/LeafC [V][160]  (unchanged)
// ---------------------------------------------------------------------------
__global__ __launch_bounds__(512) void leaf_gemm(
    const float* __restrict__ emb, const short* __restrict__ Bx,
    const float* __restrict__ bioux, const float* __restrict__ biouh,
    short* __restrict__ LeafH, short* __restrict__ LeafC)
{
    __shared__ __align__(16) char smem[LEAF_CH * 2 + 64 * 64];
    short* Bs = (short*)smem;
    short* As = (short*)(smem + LEAF_CH * 2);
    float* Es = (float*)smem;

    const int t = threadIdx.x;
    const int row0 = blockIdx.x * 64;
    const int w = t >> 6, lane = t & 63;
    const int mt = w & 3, nt0 = (w >> 2) * LEAF_NT;
    const int lr = lane & 15, quad = lane >> 4;

    f32x4 acc[LEAF_NT];
    #pragma unroll
    for (int i = 0; i < LEAF_NT; i++) { acc[i][0] = 0; acc[i][1] = 0; acc[i][2] = 0; acc[i][3] = 0; }

    const int arow = t >> 3, apart = t & 7;
    const int av = row0 + arow;
    const int aq = apart >> 1, aj = (apart & 1) * 4;

    for (int kc = 0; kc < LEAF_KC; kc++) {
        const short* bsrc = Bx + (size_t)kc * LEAF_CH;
        #pragma unroll
        for (int i = 0; i < 3; i++)
            gl_lds16(bsrc + (i * 512 + t) * 8, Bs + (i * 512 + (t & ~63)) * 8);
        if (t < 384)
            gl_lds16(bsrc + (1536 + t) * 8, Bs + (1536 + (t & ~63)) * 8);
        {
            const int k0 = kc * 32 + apart * 4;
            float4 x = make_float4(0.f, 0.f, 0.f, 0.f);
            if (av < V_ && k0 < IN_) x = *(const float4*)&emb[(size_t)av * IN_ + k0];
            short4v s;
            s[0] = f2bs(x.x); s[1] = f2bs(x.y); s[2] = f2bs(x.z); s[3] = f2bs(x.w);
            *(short4v*)&As[aq * 512 + arow * 8 + aj] = s;
        }
        __syncthreads();
        bf16x8 a = *(const bf16x8*)&As[quad * 512 + (mt * 16 + lr) * 8];
        #pragma unroll
        for (int i = 0; i < LEAF_NT; i++) {
            bf16x8 b = *(const bf16x8*)&Bs[quad * LEAF_QS + ((nt0 + i) * 16 + lr) * 8];
            acc[i] = __builtin_amdgcn_mfma_f32_16x16x32_bf16(a, b, acc[i], 0, 0, 0);
        }
        __syncthreads();
    }

    for (int mc = 0; mc < 4; mc++) {
        if (mt == mc) {
            #pragma unroll
            for (int i = 0; i < LEAF_NT; i++) {
                const int col = (nt0 + i) * 16 + lr;
                #pragma unroll
                for (int r = 0; r < 4; r++) Es[(quad * 4 + r) * LEAF_N + col] = acc[i][r];
            }
        }
        __syncthreads();
        for (int p = t; p < 16 * KP_; p += 512) {
            const int rl = p / KP_, n = p % KP_;
            const int v = row0 + mc * 16 + rl;
            if (v < V_) {
                if (n < M_) {
                    const float i_ = Es[rl * LEAF_N + n]       + bioux[n]       + biouh[n];
                    const float o_ = Es[rl * LEAF_N + n + 150] + bioux[n + 150] + biouh[n + 150];
                    const float u_ = Es[rl * LEAF_N + n + 300] + bioux[n + 300] + biouh[n + 300];
                    const float c = sgm(i_) * tanh_f(u_);
                    const float h = sgm(o_) * tanh_f(c);
                    LeafH[(size_t)v * KP_ + n] = f2bs(h);
                    LeafC[(size_t)v * KP_ + n] = f2bs(c);
                } else {
                    LeafH[(size_t)v * KP_ + n] = 0;
                    LeafC[(size_t)v * KP_ + n] = 0;
                }
            }
        }
        __syncthreads();
    }
}

// ---------------------------------------------------------------------------
// K2: per-vocab level-0 tables — 1024 threads, 16 waves (r7, proven).
// Folds 0.5*biouh into the G slots so level1's gather needs no bias.
// ---------------------------------------------------------------------------
__global__ __launch_bounds__(1024) void leafGF_gemm(
    const short* __restrict__ LeafH, const short* __restrict__ LeafC,
    const short* __restrict__ Bg2, const float* __restrict__ biouh,
    const float* __restrict__ bfh, short* __restrict__ LeafE)
{
    __shared__ __align__(16) char smem[GCH2_ * 2 + 4096 + KP_ * 64 * 2 + 2400];
    short* Bs     = (short*)smem;                        // 40960 B
    short* As     = (short*)(smem + GCH2_ * 2);          // 4096 B
    short* CinS   = (short*)(smem + GCH2_ * 2 + 4096);   // 20480 B
    float* bias_s = (float*)(smem + GCH2_ * 2 + 4096 + KP_ * 64 * 2); // 2400 B
    short* Os = (short*)smem;                            // 32*608*2 = 38912 B

    const int t = threadIdx.x;
    const int v0 = blockIdx.x * 64;
    const int w = t >> 6, lane = t & 63;
    const int mt = w & 3, nt0 = (w >> 2) * GNT2_;
    const int lr = lane & 15, quad = lane >> 4;
    const int c = lane & 15;

    if (t < 600) bias_s[t] = (t < 450) ? biouh[t] : bfh[t - 450];
    const short* csrc = LeafC + (size_t)v0 * KP_;
    gl_lds16(csrc + t * 8, CinS + (t & ~63) * 8);
    if (t < 256)
        gl_lds16(csrc + (1024 + t) * 8, CinS + (1024 + (t & ~63)) * 8);

    f32x4 acc[GNT2_];
    #pragma unroll
    for (int i = 0; i < GNT2_; i++) { acc[i][0] = 0; acc[i][1] = 0; acc[i][2] = 0; acc[i][3] = 0; }

    const int arow = t & 63, apart = t >> 6;   // apart 0..3 for t<256
    const size_t srow = (size_t)((v0 + arow < V_) ? (v0 + arow) : 0);
    const short* asrc = LeafH + srow * KP_ + apart * 8;

    for (int kc = 0; kc < GKC_; kc++) {
        const short* bsrc = Bg2 + (size_t)kc * GCH2_;
        #pragma unroll
        for (int i = 0; i < 2; i++)
            gl_lds16(bsrc + (i * 1024 + t) * 8, Bs + (i * 1024 + (t & ~63)) * 8);
        if (t < 512)
            gl_lds16(bsrc + (2048 + t) * 8, Bs + (2048 + (t & ~63)) * 8);
        if (t < 256)
            gl_lds16(asrc + kc * 32, As + (t & ~63) * 8);
        __syncthreads();
        bf16x8 a = *(const bf16x8*)&As[quad * 512 + (mt * 16 + lr) * 8];
        #pragma unroll
        for (int i = 0; i < GNT2_; i++) {
            bf16x8 b = *(const bf16x8*)&Bs[quad * GQS2_ + ((nt0 + i) * 16 + lr) * 8];
            acc[i] = __builtin_amdgcn_mfma_f32_16x16x32_bf16(a, b, acc[i], 0, 0, 0);
        }
        __syncthreads();
    }

    for (int ph = 0; ph < 2; ph++) {
        if ((mt >> 1) == ph) {
            const int rbase = 16 * (mt & 1) + 4 * quad;
            #pragma unroll
            for (int i = 0; i < GNT2_; i++) {
                const int col = (nt0 + i) * 16 + c;
                if (col < GN_) {
                    const int m = col >> 2, g = col & 3;
                    #pragma unroll
                    for (int r = 0; r < 4; r++) {
                        short ov;
                        if (g == 3) {
                            if (m < M_) {
                                const float cc = bs2f(CinS[(32 * ph + rbase + r) * KP_ + m]);
                                ov = f2bs(sgm(acc[i][r] + bias_s[450 + m]) * cc);
                            } else ov = 0;
                        } else {
                            float gv = acc[i][r];
                            if (m < M_) gv += 0.5f * bias_s[g * 150 + m];  // fold bias
                            ov = f2bs(gv);
                        }
                        Os[(rbase + r) * GN_ + col] = ov;
                    }
                }
            }
        }
        __syncthreads();
        const int vb = v0 + 32 * ph;
        const int4* os4 = (const int4*)Os;
        for (int u = t; u < 2432; u += 1024) {
            const int row = u / 76;
            if (vb + row < V_)
                ((int4*)(LeafE + (size_t)(vb + row) * GN_))[u - row * 76] = os4[u];
        }
        __syncthreads();
    }
}

// ---------------------------------------------------------------------------
// Shared in-register LSTM epilogue (gate-interleaved C) for level_gemm.
// ---------------------------------------------------------------------------
template<int CS, int TNT>
__device__ __forceinline__ void level_epilogue(
    const f32x4* acc, int mt, int nt0, int lane,
    const short* CinS, const float* bias_s, short* Hs, short* Cs)
{
    const int q = lane >> 4, c = lane & 15, g = c & 3, lb = lane & ~3;
    #pragma unroll
    for (int i = 0; i < TNT; i++) {
        const int col = (nt0 + i) * 16 + c;
        const int m = col >> 2;
        const float vA = acc[i][0] + acc[i][1];
        const float vB = acc[i][2] + acc[i][3];
        const float iA = __shfl(vA, lb), oA = __shfl(vA, lb + 1), uA = __shfl(vA, lb + 2);
        const float iB = __shfl(vB, lb), oB = __shfl(vB, lb + 1), uB = __shfl(vB, lb + 2);
        const float fA0 = __shfl(acc[i][0], lb + 3), fA1 = __shfl(acc[i][1], lb + 3);
        const float fB0 = __shfl(acc[i][2], lb + 3), fB1 = __shfl(acc[i][3], lb + 3);
        if (g < 2 && m < M_) {
            const float iv = g ? iB : iA, ov = g ? oB : oA, uv = g ? uB : uA;
            const float fl = g ? fB0 : fA0, fr = g ? fB1 : fA1;
            const int node = 8 * mt + 2 * q + g;
            const int ch = 16 * mt + 4 * q + 2 * g;
            const float cl = bs2f(CinS[ch * CS + m]);
            const float cr = bs2f(CinS[(ch + 1) * CS + m]);
            const float bf = bias_s[450 + m];
            const float cv = sgm(iv + bias_s[m]) * tanh_f(uv + bias_s[m + 300])
                           + sgm(fl + bf) * cl + sgm(fr + bf) * cr;
            const float hv = sgm(ov + bias_s[m + 150]) * tanh_f(cv);
            Hs[node * KP_ + m] = f2bs(hv);
            Cs[node * KP_ + m] = f2bs(cv);
        }
    }
}

// ---------------------------------------------------------------------------
// level1 helpers: per-half epilogue to PACKED REGISTERS, bias from global.
// ---------------------------------------------------------------------------
template<int T0, int TN>
__device__ __forceinline__ void epi_half_pack(
    const f32x4* acc, int mt, int nt0, int lane, const short* CinS,
    const float* __restrict__ biouh, const float* __restrict__ bfh,
    unsigned int* pack)
{
    const int q = lane >> 4, c = lane & 15, g = c & 3, lb = lane & ~3;
    #pragma unroll
    for (int i = 0; i < TN; i++) {
        const int col = (nt0 + T0 + i) * 16 + c;
        const int m = col >> 2;
        const float vA = acc[i][0] + acc[i][1];
        const float vB = acc[i][2] + acc[i][3];
        const float iA = __shfl(vA, lb), oA = __shfl(vA, lb + 1), uA = __shfl(vA, lb + 2);
        const float iB = __shfl(vB, lb), oB = __shfl(vB, lb + 1), uB = __shfl(vB, lb + 2);
        const float fA0 = __shfl(acc[i][0], lb + 3), fA1 = __shfl(acc[i][1], lb + 3);
        const float fB0 = __shfl(acc[i][2], lb + 3), fB1 = __shfl(acc[i][3], lb + 3);
        unsigned int pk = 0;
        if (g < 2 && m < M_) {
            const float iv = g ? iB : iA, ov = g ? oB : oA, uv = g ? uB : uA;
            const float fl = g ? fB0 : fA0, fr = g ? fB1 : fA1;
            const int ch = 16 * mt + 4 * q + 2 * g;
            const float cl = bs2f(CinS[ch * 152 + m]);
            const float cr = bs2f(CinS[(ch + 1) * 152 + m]);
            const float bf = bfh[m];
            const float cv = sgm(iv + biouh[m]) * tanh_f(uv + biouh[m + 300])
                           + sgm(fl + bf) * cl + sgm(fr + bf) * cr;
            const float hv = sgm(ov + biouh[m + 150]) * tanh_f(cv);
            pk = ((unsigned int)(unsigned short)f2bs(hv) << 16)
               |  (unsigned int)(unsigned short)f2bs(cv);
        }
        pack[i] = pk;
    }
}

template<int T0, int TN>
__device__ __forceinline__ void unpack_half(
    const unsigned int* pack, int mt, int nt0, int lane, short* Hs, short* Cs)
{
    const int q = lane >> 4, c = lane & 15, g = c & 3;
    #pragma unroll
    for (int i = 0; i < TN; i++) {
        const int col = (nt0 + T0 + i) * 16 + c;
        const int m = col >> 2;
        if (g < 2 && m < M_) {
            const int node = 8 * mt + 2 * q + g;
            Hs[node * KP_ + m] = (short)(pack[i] >> 16);
            Cs[node * KP_ + m] = (short)(pack[i] & 0xffff);
        }
    }
}

// ---------------------------------------------------------------------------
// K3: level 1 with fused level-0 gather — 512 threads, (512,4), 2 blocks/CU,
// N-SPLIT K-loop (10+9). BgS split-pack: each pass stages ONLY its own tile
// columns (20480 B / 18432 B per kc vs 38912 B). Bs = 20480 B; LDS = 60416 B.
// ---------------------------------------------------------------------------
__global__ __launch_bounds__(512, 4) void level1_fused(
    const int* __restrict__ ltok, const int* __restrict__ rtok,
    const short* __restrict__ LeafE, const short* __restrict__ BgS,
    const float* __restrict__ biouh, const float* __restrict__ bfh,
    short* __restrict__ Hout, short* __restrict__ Cout)
{
    constexpr int CS1 = 152;                                   // CinS row stride
    __shared__ __align__(16) char smem[20480 + 20480 + 64 * CS1 * 2]; // 60416 B
    short* Bs     = (short*)smem;                              // 20480 B
    short* AsF    = (short*)(smem + 20480);                    // 20480 B persistent A
    short* CinS   = (short*)(smem + 40960);                    // 19456 B
    short* Hs = Bs;
    short* Cs = Bs + 32 * KP_;

    const int t = threadIdx.x;
    const int out0 = blockIdx.x * 32;
    const int w = t >> 6, lane = t & 63;
    const int mt = w & 3, nq = w >> 2, nt0 = nq * GNT_;
    const int lr = lane & 15, quad = lane >> 4;

    // ---- fused level-0 gather: 64 node h/c rows into AsF / CinS (no bias) --
    {
        const int row = t >> 3, qs = t & 7;
        const int gidx = blockIdx.x * 128 + 2 * row;
        const int* tsrc = (gidx < B_ * L_) ? (ltok + gidx) : (rtok + gidx - B_ * L_);
        const short* el = LeafE + (size_t)tsrc[0] * GN_;
        const short* er = LeafE + (size_t)tsrc[1] * GN_;

        union U { int4 v[2]; short s16[16]; };
        U ue, ur, uen, urn;
        ue.v[0] = *(const int4*)(el + qs * 16);
        ue.v[1] = *(const int4*)(el + qs * 16 + 8);
        ur.v[0] = *(const int4*)(er + qs * 16);
        ur.v[1] = *(const int4*)(er + qs * 16 + 8);

        #pragma unroll 1
        for (int s = 0; s < 5; s++) {
            const int Q  = qs + 8 * s;
            const int Qn = Q + 8;
            if (s < 4 && Qn < 38) {
                uen.v[0] = *(const int4*)(el + Qn * 16);
                uen.v[1] = *(const int4*)(el + Qn * 16 + 8);
                urn.v[0] = *(const int4*)(er + Qn * 16);
                urn.v[1] = *(const int4*)(er + Qn * 16 + 8);
            }
            short4v hq = {0, 0, 0, 0}, cq = {0, 0, 0, 0};
            if (Q < 38) {
                #pragma unroll
                for (int jj = 0; jj < 4; jj++) {
                    const int m = 4 * Q + jj;
                    if (m < M_) {
                        const float i_ = bs2f(ue.s16[4 * jj])     + bs2f(ur.s16[4 * jj]);
                        const float o_ = bs2f(ue.s16[4 * jj + 1]) + bs2f(ur.s16[4 * jj + 1]);
                        const float u_ = bs2f(ue.s16[4 * jj + 2]) + bs2f(ur.s16[4 * jj + 2]);
                        const float fc = bs2f(ue.s16[4 * jj + 3]) + bs2f(ur.s16[4 * jj + 3]);
                        const float cv = sgm(i_) * tanh_f(u_) + fc;
                        const float hv = sgm(o_) * tanh_f(cv);
                        hq[jj] = f2bs(hv); cq[jj] = f2bs(cv);
                    }
                }
            }
            const int m0 = 4 * Q;
            const int kc = m0 >> 5, q = (m0 >> 3) & 3, j0 = m0 & 7;
            *(short4v*)&AsF[(kc * 4 + q) * 512 + row * 8 + j0] = hq;   // zeros pad A
            if (Q < 38)
                *(short4v*)&CinS[row * CS1 + m0] = cq;
            ue = uen; ur = urn;
        }
    }

    unsigned int packA[10], packB[9];
    f32x4 acc[10];

    // -------- N-half 0: global tiles nt0+0..9 = BgS sec-0 slots nq*10+i ----
    #pragma unroll
    for (int i = 0; i < 10; i++) { acc[i][0] = 0; acc[i][1] = 0; acc[i][2] = 0; acc[i][3] = 0; }
    for (int kc = 0; kc < GKC_; kc++) {
        const short* bsrc = BgS + (size_t)kc * S0_CH;
        #pragma unroll
        for (int i = 0; i < 2; i++)
            gl_lds16(bsrc + (i * 512 + t) * 8, Bs + (i * 512 + (t & ~63)) * 8);
        if (t < 256)
            gl_lds16(bsrc + (1024 + t) * 8, Bs + (1024 + (t & ~63)) * 8);
        __syncthreads();
        bf16x8 a = *(const bf16x8*)&AsF[kc * 2048 + quad * 512 + (mt * 16 + lr) * 8];
        #pragma unroll
        for (int i = 0; i < 10; i++) {
            bf16x8 b = *(const bf16x8*)&Bs[quad * S0_QS + ((nq * 10 + i) * 16 + lr) * 8];
            acc[i] = __builtin_amdgcn_mfma_f32_16x16x32_bf16(a, b, acc[i], 0, 0, 0);
        }
        __syncthreads();
    }
    epi_half_pack<0, 10>(acc, mt, nt0, lane, CinS, biouh, bfh, packA);

    // -------- N-half 1: global tiles nt0+10..18 = BgS sec-1 slots nq*9+i ---
    #pragma unroll
    for (int i = 0; i < 9; i++) { acc[i][0] = 0; acc[i][1] = 0; acc[i][2] = 0; acc[i][3] = 0; }
    for (int kc = 0; kc < GKC_; kc++) {
        const short* bsrc = BgS + S0_TOT + (size_t)kc * S1_CH;
        #pragma unroll
        for (int i = 0; i < 2; i++)
            gl_lds16(bsrc + (i * 512 + t) * 8, Bs + (i * 512 + (t & ~63)) * 8);
        if (t < 128)
            gl_lds16(bsrc + (1024 + t) * 8, Bs + (1024 + (t & ~63)) * 8);
        __syncthreads();
        bf16x8 a = *(const bf16x8*)&AsF[kc * 2048 + quad * 512 + (mt * 16 + lr) * 8];
        #pragma unroll
        for (int i = 0; i < 9; i++) {
            bf16x8 b = *(const bf16x8*)&Bs[quad * S1_QS + ((nq * 9 + i) * 16 + lr) * 8];
            acc[i] = __builtin_amdgcn_mfma_f32_16x16x32_bf16(a, b, acc[i], 0, 0, 0);
        }
        __syncthreads();
    }
    epi_half_pack<10, 9>(acc, mt, nt0, lane, CinS, biouh, bfh, packB);

    // -------- write phase: unpack into Hs/Cs (Bs now dead) --------
    if (t < 320) { const int node = t / 10, mm = 150 + t % 10;
                   Hs[node * KP_ + mm] = 0; Cs[node * KP_ + mm] = 0; }
    unpack_half<0, 10>(packA, mt, nt0, lane, Hs, Cs);
    unpack_half<10, 9>(packB, mt, nt0, lane, Hs, Cs);
    __syncthreads();
    int4* Hg = (int4*)(Hout + (size_t)out0 * KP_);
    int4* Cg = (int4*)(Cout + (size_t)out0 * KP_);
    const int4* hs4 = (const int4*)Hs;
    const int4* cs4 = (const int4*)Cs;
    for (int u = t; u < 1280; u += 512) {
        if (u < 640) Hg[u] = hs4[u]; else Cg[u - 640] = cs4[u - 640];
    }
}

// ---------------------------------------------------------------------------
// K4: internal levels 2..5 — 1024 threads, 16 waves, Bg2 (r7, proven).
// ---------------------------------------------------------------------------
__global__ __launch_bounds__(1024) void level_gemm(
    const short* __restrict__ Hin, const short* __restrict__ Cin,
    const short* __restrict__ Bg2,
    const float* __restrict__ biouh, const float* __restrict__ bfh,
    short* __restrict__ Hout, short* __restrict__ Cout)
{
    __shared__ __align__(16) char smem[GCH2_ * 2 + 4096 + 20480 + 2400];
    short* Bs     = (short*)smem;                        // 40960 B
    short* As     = (short*)(smem + GCH2_ * 2);
    short* CinS   = (short*)(smem + GCH2_ * 2 + 4096);
    float* bias_s = (float*)(smem + GCH2_ * 2 + 4096 + 20480);
    short* Hs = Bs;
    short* Cs = Bs + 32 * KP_;

    const int t = threadIdx.x;
    const int row0 = blockIdx.x * 64, out0 = blockIdx.x * 32;
    const int w = t >> 6, lane = t & 63;
    const int mt = w & 3, nt0 = (w >> 2) * GNT2_;
    const int lr = lane & 15, quad = lane >> 4;

    if (t < 600) bias_s[t] = (t < 450) ? biouh[t] : bfh[t - 450];
    const short* csrc = Cin + (size_t)row0 * KP_;
    gl_lds16(csrc + t * 8, CinS + (t & ~63) * 8);
    if (t < 256)
        gl_lds16(csrc + (1024 + t) * 8, CinS + (1024 + (t & ~63)) * 8);

    f32x4 acc[GNT2_];
    #pragma unroll
    for (int i = 0; i < GNT2_; i++) { acc[i][0] = 0; acc[i][1] = 0; acc[i][2] = 0; acc[i][3] = 0; }

    const short* asrc = Hin + (size_t)(row0 + (t & 63)) * KP_ + (t >> 6) * 8;

    for (int kc = 0; kc < GKC_; kc++) {
        const short* bsrc = Bg2 + (size_t)kc * GCH2_;
        #pragma unroll
        for (int i = 0; i < 2; i++)
            gl_lds16(bsrc + (i * 1024 + t) * 8, Bs + (i * 1024 + (t & ~63)) * 8);
        if (t < 512)
            gl_lds16(bsrc + (2048 + t) * 8, Bs + (2048 + (t & ~63)) * 8);
        if (t < 256)
            gl_lds16(asrc + kc * 32, As + (t & ~63) * 8);
        __syncthreads();
        bf16x8 a = *(const bf16x8*)&As[quad * 512 + (mt * 16 + lr) * 8];
        #pragma unroll
        for (int i = 0; i < GNT2_; i++) {
            bf16x8 b = *(const bf16x8*)&Bs[quad * GQS2_ + ((nt0 + i) * 16 + lr) * 8];
            acc[i] = __builtin_amdgcn_mfma_f32_16x16x32_bf16(a, b, acc[i], 0, 0, 0);
        }
        __syncthreads();
    }

    if (t < 320) { const int node = t / 10, mm = 150 + t % 10;
                   Hs[node * KP_ + mm] = 0; Cs[node * KP_ + mm] = 0; }
    level_epilogue<KP_, GNT2_>(acc, mt, nt0, lane, CinS, bias_s, Hs, Cs);
    __syncthreads();
    int4* Hg = (int4*)(Hout + (size_t)out0 * KP_);
    int4* Cg = (int4*)(Cout + (size_t)out0 * KP_);
    const int4* hs4 = (const int4*)Hs;
    const int4* cs4 = (const int4*)Cs;
    for (int u = t; u < 1280; u += 1024) {
        if (u < 640) Hg[u] = hs4[u]; else Cg[u - 640] = cs4[u - 640];
    }
}

// ---------------------------------------------------------------------------
// K5: similarity head (one wave per pair).
// ---------------------------------------------------------------------------
__global__ __launch_bounds__(64) void head_kernel(
    const short* __restrict__ RootH,
    const float* __restrict__ Wh, const float* __restrict__ bh,
    const float* __restrict__ Wp, const float* __restrict__ bp,
    float* __restrict__ out)
{
    __shared__ float vec[2 * M_];
    __shared__ float mid[HID_];
    __shared__ float lg[NC_];
    __shared__ float lse;

    const int b = blockIdx.x;
    const int t = threadIdx.x;
    const short* lh = RootH + (size_t)b * KP_;
    const short* rh = RootH + (size_t)(B_ + b) * KP_;

    for (int i = t; i < M_; i += 64) {
        const float a = bs2f(lh[i]), c = bs2f(rh[i]);
        vec[i]      = a * c;
        vec[M_ + i] = fabsf(a - c);
    }
    __syncthreads();

    for (int j = t; j < HID_; j += 64) {
        float acc = bh[j];
        for (int k = 0; k < 2 * M_; k++) acc += vec[k] * Wh[k * HID_ + j];
        mid[j] = sgm(acc);
    }
    __syncthreads();

    if (t < NC_) {
        float acc = bp[t];
        for (int k = 0; k < HID_; k++) acc += mid[k] * Wp[k * NC_ + t];
        lg[t] = acc;
    }
    __syncthreads();

    if (t == 0) {
        float mx = lg[0];
        for (int i = 1; i < NC_; i++) mx = fmaxf(mx, lg[i]);
        float s = 0.0f;
        for (int i = 0; i < NC_; i++) s += expf(lg[i] - mx);
        lse = mx + logf(s);
    }
    __syncthreads();

    if (t < NC_) out[b * NC_ + t] = lg[t] - lse;
}

// ---------------------------------------------------------------------------
extern "C" void kernel_launch(void* const* d_in, const int* in_sizes, int n_in,
                              void* d_out, int out_size, void* d_ws, size_t ws_size,
                              hipStream_t stream)
{
    const int*   ltok  = (const int*)d_in[0];
    const int*   rtok  = (const int*)d_in[1];
    const float* emb   = (const float*)d_in[2];
    const float* Wioux = (const float*)d_in[3];
    const float* bioux = (const float*)d_in[4];
    const float* Wiouh = (const float*)d_in[5];
    const float* biouh = (const float*)d_in[6];
    const float* Wfh   = (const float*)d_in[9];
    const float* bfh   = (const float*)d_in[10];
    const float* Wh    = (const float*)d_in[11];
    const float* bh    = (const float*)d_in[12];
    const float* Wp    = (const float*)d_in[13];
    const float* bp    = (const float*)d_in[14];
    float* out = (float*)d_out;

    char* ws = (char*)d_ws;
    size_t off = 0;
    auto carve = [&](size_t bytes) { char* p = ws + off; off += (bytes + 255) & ~(size_t)255; return p; };
    short* BgS   = (short*)carve((size_t)(S0_TOT + S1_TOT) * 2);
    short* Bg2   = (short*)carve((size_t)GKC_ * GCH2_ * 2);
    short* Bx    = (short*)carve((size_t)LEAF_KC * LEAF_CH * 2);
    short* LeafH = (short*)carve((size_t)V_ * KP_ * 2);      // 16 MB
    short* LeafC = (short*)carve((size_t)V_ * KP_ * 2);      // 16 MB
    short* LeafE = (short*)carve((size_t)V_ * GN_ * 2);      // 60.8 MB
    short* HA    = (short*)carve((size_t)65536 * KP_ * 2);   // 21 MB
    short* CA    = (short*)carve((size_t)65536 * KP_ * 2);   // 21 MB
    short* HB    = (short*)carve((size_t)32768 * KP_ * 2);   // 10.5 MB
    short* CB    = (short*)carve((size_t)32768 * KP_ * 2);   // 10.5 MB

    hipLaunchKernelGGL(prep_kernel, dim3(128), dim3(256), 0, stream, Wioux, Wiouh, Wfh, BgS, Bg2, Bx);
    hipLaunchKernelGGL(leaf_gemm, dim3((V_ + 63) / 64), dim3(512), 0, stream,
                       emb, Bx, bioux, biouh, LeafH, LeafC);
    hipLaunchKernelGGL(leafGF_gemm, dim3((V_ + 63) / 64), dim3(1024), 0, stream,
                       LeafH, LeafC, Bg2, biouh, bfh, LeafE);
    // level 1 (fused level-0 gather): 131072 nodes -> 65536 rows
    hipLaunchKernelGGL(level1_fused, dim3(2048), dim3(512), 0, stream,
                       ltok, rtok, LeafE, BgS, biouh, bfh, HA, CA);
    // levels 2..5
    hipLaunchKernelGGL(level_gemm, dim3(1024), dim3(1024), 0, stream,
                       HA, CA, Bg2, biouh, bfh, HB, CB);
    hipLaunchKernelGGL(level_gemm, dim3(512), dim3(1024), 0, stream,
                       HB, CB, Bg2, biouh, bfh, HA, CA);
    hipLaunchKernelGGL(level_gemm, dim3(256), dim3(1024), 0, stream,
                       HA, CA, Bg2, biouh, bfh, HB, CB);
    hipLaunchKernelGGL(level_gemm, dim3(128), dim3(1024), 0, stream,
                       HB, CB, Bg2, biouh, bfh, HA, CA);
    hipLaunchKernelGGL(head_kernel, dim3(B_), dim3(64), 0, stream, HA, Wh, bh, Wp, bp, out);
}